// Round 2
// baseline (1353.827 us; speedup 1.0000x reference)
//
#include <hip/hip_runtime.h>
#include <stdint.h>

typedef unsigned short ushort_t;
typedef __bf16 bf16x8 __attribute__((ext_vector_type(8)));
typedef float f32x4 __attribute__((ext_vector_type(4)));

#define T_SEQ 4096
#define D_MODEL 896

// Fano lines, residues sorted ascending per head
__constant__ int d_LINEMASK[7] = {0x07, 0x19, 0x61, 0x2A, 0x52, 0x4C, 0x34};
__constant__ int d_R[7][3] = {{0,1,2},{0,3,4},{0,5,6},{1,3,5},{1,4,6},{2,3,6},{2,4,5}};

__device__ inline unsigned f2bf(float f) {
    unsigned x = __float_as_uint(f);
    return (x + 0x7fffu + ((x >> 16) & 1u)) >> 16;   // RNE
}
__device__ inline float lo_f(unsigned x) { return __uint_as_float(x << 16); }
__device__ inline float hi_f(unsigned x) { return __uint_as_float(x & 0xFFFF0000u); }
__device__ inline void unpack8(uint4 u, float* f) {
    f[0] = lo_f(u.x); f[1] = hi_f(u.x);
    f[2] = lo_f(u.y); f[3] = hi_f(u.y);
    f[4] = lo_f(u.z); f[5] = hi_f(u.z);
    f[6] = lo_f(u.w); f[7] = hi_f(u.w);
}

// ---------------------------------------------------------------------------
// Runtime dtype probe: sample 2048 u32 words of x. If data is bf16, the low
// u16 of each word is a genuine ~N(0,1) bf16 (exponent in narrow band). If
// data is fp32, the low u16 is mantissa junk (uniform). flag=1 -> fp32.
// ---------------------------------------------------------------------------
__global__ void detect_dtype(const uint32_t* __restrict__ x, int* __restrict__ flag) {
    const int lane = threadIdx.x;  // 64 threads, 1 wave
    int cnt = 0;
#pragma unroll
    for (int r = 0; r < 8; r++) {
        uint4 w = *(const uint4*)&x[(size_t)(r * 64 + lane) * 4];
        uint32_t v[4] = {w.x, w.y, w.z, w.w};
#pragma unroll
        for (int q = 0; q < 4; q++) {
            uint32_t lo = v[q] & 0xFFFFu;
            int e = (lo >> 7) & 0xFF;
            if (lo == 0u || (e >= 0x58 && e <= 0xA0)) cnt++;
        }
    }
#pragma unroll
    for (int o = 32; o > 0; o >>= 1) cnt += __shfl_down(cnt, o);
    if (lane == 0) flag[0] = (cnt < 1300) ? 1 : 0;   // 1 = fp32, 0 = bf16
}

// stage 8 consecutive elements (bf16 passthrough or fp32->bf16) into LDS
__device__ inline void stage8(const void* P, bool is32, size_t off, ushort_t* dst) {
    if (is32) {
        const float* p = (const float*)P + off;
        float4 a = *(const float4*)p;
        float4 b = *(const float4*)(p + 4);
        uint4 u;
        u.x = f2bf(a.x) | (f2bf(a.y) << 16);
        u.y = f2bf(a.z) | (f2bf(a.w) << 16);
        u.z = f2bf(b.x) | (f2bf(b.y) << 16);
        u.w = f2bf(b.z) | (f2bf(b.w) << 16);
        *(uint4*)dst = u;
    } else {
        *(uint4*)dst = *(const uint4*)((const ushort_t*)P + off);
    }
}

// ---------------------------------------------------------------------------
// C[M,N] = A[M,K] @ B[N,K]^T  (fp32 acc). M=4096, N=K=896.
// 128x128 tile, BK=32, 256 thr = 4 waves (2x2 of 64x64 per-wave tiles).
// blockIdx.z selects which (B, C) pair -> fuses Q/K/V projections.
// mode: 0 = bf16, 1 = fp32, 2 = follow runtime flag.
// ---------------------------------------------------------------------------
__global__ void gemm_nt(const void* __restrict__ A,
                        const void* __restrict__ B0,
                        const void* __restrict__ B1,
                        const void* __restrict__ B2,
                        void* __restrict__ C0,
                        void* __restrict__ C1,
                        void* __restrict__ C2,
                        const int* __restrict__ flag,
                        int amode, int bmode, int cmode) {
    const int z = blockIdx.z;
    const void* B = (z == 0) ? B0 : (z == 1) ? B1 : B2;
    void* C = (z == 0) ? C0 : (z == 1) ? C1 : C2;

    const int f = flag[0];
    const bool a32 = (amode == 2) ? (f != 0) : (amode == 1);
    const bool b32 = (bmode == 2) ? (f != 0) : (bmode == 1);
    const bool c32 = (cmode == 2) ? (f != 0) : (cmode == 1);

    const int K = D_MODEL, N = D_MODEL;
    const int i0 = blockIdx.x * 128;
    const int n0 = blockIdx.y * 128;

    __shared__ __align__(16) ushort_t As[128 * 32];
    __shared__ __align__(16) ushort_t Bs[128 * 32];

    const int t = threadIdx.x;
    const int w = t >> 6, l = t & 63;
    const int wm = (w >> 1) * 64, wn = (w & 1) * 64;
    const int lr = l & 15, lq = l >> 4;

    f32x4 acc[4][4];
#pragma unroll
    for (int a = 0; a < 4; a++)
#pragma unroll
        for (int b = 0; b < 4; b++) acc[a][b] = (f32x4){0.f, 0.f, 0.f, 0.f};

    for (int kt = 0; kt < K / 32; kt++) {
        const int k0 = kt * 32;
        __syncthreads();
#pragma unroll
        for (int rep = 0; rep < 2; rep++) {
            int q = t + rep * 256;
            int row = q >> 2, c16 = (q & 3) * 8;
            stage8(A, a32, (size_t)(i0 + row) * K + k0 + c16, &As[row * 32 + c16]);
            stage8(B, b32, (size_t)(n0 + row) * K + k0 + c16, &Bs[row * 32 + c16]);
        }
        __syncthreads();

        bf16x8 af[4], bfr[4];
#pragma unroll
        for (int mi = 0; mi < 4; mi++)
            af[mi] = *(const bf16x8*)&As[(wm + mi * 16 + lr) * 32 + lq * 8];
#pragma unroll
        for (int ni = 0; ni < 4; ni++)
            bfr[ni] = *(const bf16x8*)&Bs[(wn + ni * 16 + lr) * 32 + lq * 8];
#pragma unroll
        for (int mi = 0; mi < 4; mi++)
#pragma unroll
            for (int ni = 0; ni < 4; ni++)
                acc[mi][ni] = __builtin_amdgcn_mfma_f32_16x16x32_bf16(
                    af[mi], bfr[ni], acc[mi][ni], 0, 0, 0);
    }

    // C/D layout: col = lane&15, row = (lane>>4)*4 + reg
    if (c32) {
        float* Cf = (float*)C;
#pragma unroll
        for (int mi = 0; mi < 4; mi++)
#pragma unroll
            for (int ni = 0; ni < 4; ni++)
#pragma unroll
                for (int r = 0; r < 4; r++) {
                    int row = i0 + wm + mi * 16 + lq * 4 + r;
                    int col = n0 + wn + ni * 16 + lr;
                    Cf[(size_t)row * N + col] = acc[mi][ni][r];
                }
    } else {
        ushort_t* Cb = (ushort_t*)C;
#pragma unroll
        for (int mi = 0; mi < 4; mi++)
#pragma unroll
            for (int ni = 0; ni < 4; ni++)
#pragma unroll
                for (int r = 0; r < 4; r++) {
                    int row = i0 + wm + mi * 16 + lq * 4 + r;
                    int col = n0 + wn + ni * 16 + lr;
                    Cb[(size_t)row * N + col] = (ushort_t)f2bf(acc[mi][ni][r]);
                }
    }
}

// ---------------------------------------------------------------------------
// Fano sparse attention (bf16 in/out, fp32 math). Grid (T/64, 7). Block 256.
// Lane: row = wid*16 + (lane>>2), channel slice = (lane&3)*32.
// Fano part iterates COMPACTED keys j = 7*(p/3) + r[p%3] (monotone in p),
// window part adds j in [i-16, i] with j%7 not in line (disjoint union).
// ---------------------------------------------------------------------------
__global__ void fano_attn(const ushort_t* __restrict__ Qb,
                          const ushort_t* __restrict__ Kb,
                          const ushort_t* __restrict__ Vb,
                          ushort_t* __restrict__ Ab) {
    const int h = blockIdx.y;
    const int i0 = blockIdx.x * 64;
    const int t = threadIdx.x;
    const int wid = t >> 6, lane = t & 63;
    const int rloc = wid * 16 + (lane >> 2);
    const int i = i0 + rloc;
    const int sub = lane & 3;
    const int cbase = h * 128 + sub * 32;

    __shared__ __align__(16) float Ks[64][128];
    __shared__ __align__(16) float Vs[64][128];

    const int lm = d_LINEMASK[h];
    const int r0 = d_R[h][0], r1 = d_R[h][1], r2 = d_R[h][2];
    const float scale = 0.08838834764831845f;

    float q[32];
    {
        const ushort_t* qp = Qb + (size_t)i * D_MODEL + cbase;
#pragma unroll
        for (int v4 = 0; v4 < 4; v4++) unpack8(*(const uint4*)(qp + v4 * 8), &q[v4 * 8]);
    }

    float acc[32];
#pragma unroll
    for (int c = 0; c < 32; c++) acc[c] = 0.f;
    float m = -1e30f, lsum = 0.f;

    const int imax = i0 + 63;
    const int ncomp = (imax - r0) / 7 + (imax - r1) / 7 + (imax - r2) / 7 + 3;
    const int nch = (ncomp + 63) >> 6;

    const int skk = t >> 2;           // staging: key slot within chunk
    const int ssub = (t & 3) * 32;    // staging: dim base

    for (int cc = 0; cc < nch; cc++) {
        const int base = cc * 64;
        __syncthreads();
        {   // stage 64 compacted keys of K and V as fp32
            int p = base + skk;
            int g = p / 3, rsel = p - 3 * g;
            int rr = (rsel == 0) ? r0 : (rsel == 1) ? r1 : r2;
            int j = 7 * g + rr;
            float* kd = &Ks[skk][ssub];
            float* vd = &Vs[skk][ssub];
            if (j < T_SEQ) {
                const ushort_t* kp = Kb + (size_t)j * D_MODEL + h * 128 + ssub;
                const ushort_t* vp = Vb + (size_t)j * D_MODEL + h * 128 + ssub;
#pragma unroll
                for (int v4 = 0; v4 < 4; v4++) {
                    unpack8(*(const uint4*)(kp + v4 * 8), kd + v4 * 8);
                    unpack8(*(const uint4*)(vp + v4 * 8), vd + v4 * 8);
                }
            } else {
#pragma unroll
                for (int c = 0; c < 32; c++) { kd[c] = 0.f; vd[c] = 0.f; }
            }
        }
        __syncthreads();

        // wave-uniform skip: chunk entirely beyond this wave's rows
        // (j is monotone in p, so chunk min j = j(base))
        {
            int g0 = base / 3, rs0 = base - 3 * g0;
            int jmin = 7 * g0 + ((rs0 == 0) ? r0 : (rs0 == 1) ? r1 : r2);
            int wmax = i0 + wid * 16 + 15;
            if (jmin > wmax) continue;
        }

#pragma unroll 1
        for (int sc = 0; sc < 4; sc++) {
            float s[16];
            int p = base + sc * 16;
            int g = p / 3;
            int pi = p - 3 * g, m7 = 7 * g;
            float cmax = -1e30f;
#pragma unroll
            for (int kk = 0; kk < 16; kk++) {
                const float* kr = &Ks[sc * 16 + kk][sub * 32];
                float d = 0.f;
#pragma unroll
                for (int c = 0; c < 32; c++) d += q[c] * kr[c];
                d += __shfl_xor(d, 1);
                d += __shfl_xor(d, 2);
                int j = m7 + ((pi == 0) ? r0 : (pi == 1) ? r1 : r2);
                pi++; if (pi == 3) { pi = 0; m7 += 7; }
                s[kk] = (j <= i) ? d * scale : -1e30f;
                cmax = fmaxf(cmax, s[kk]);
            }
            if (cmax > -1e29f) {
                float mn = fmaxf(m, cmax);
                float alpha = __expf(m - mn);
                lsum *= alpha;
#pragma unroll
                for (int c = 0; c < 32; c++) acc[c] *= alpha;
                m = mn;
#pragma unroll
                for (int kk = 0; kk < 16; kk++) {
                    float pw = __expf(s[kk] - m);
                    lsum += pw;
                    const float* vr = &Vs[sc * 16 + kk][sub * 32];
#pragma unroll
                    for (int c = 0; c < 32; c++) acc[c] += pw * vr[c];
                }
            }
        }
    }

    // local window: j in [i-16, i], j%7 NOT in line (disjoint from fano part)
#pragma unroll 1
    for (int dd = 0; dd < 17; dd++) {
        int j = i - 16 + dd;
        bool valid = (j >= 0) && (((lm >> (j % 7)) & 1) == 0);
        if (valid) {
            const ushort_t* kp = Kb + (size_t)j * D_MODEL + cbase;
            float d = 0.f;
#pragma unroll
            for (int v4 = 0; v4 < 4; v4++) {
                float kf[8];
                unpack8(*(const uint4*)(kp + v4 * 8), kf);
#pragma unroll
                for (int c = 0; c < 8; c++) d += q[v4 * 8 + c] * kf[c];
            }
            d += __shfl_xor(d, 1);
            d += __shfl_xor(d, 2);
            d *= scale;
            float mn = fmaxf(m, d);
            float alpha = __expf(m - mn);
            float pw = __expf(d - mn);
            lsum = lsum * alpha + pw;
            m = mn;
            const ushort_t* vp = Vb + (size_t)j * D_MODEL + cbase;
#pragma unroll
            for (int v4 = 0; v4 < 4; v4++) {
                float vf[8];
                unpack8(*(const uint4*)(vp + v4 * 8), vf);
#pragma unroll
                for (int c = 0; c < 8; c++)
                    acc[v4 * 8 + c] = acc[v4 * 8 + c] * alpha + pw * vf[c];
            }
        }
    }

    // finalize (lsum > 0: j==i is always in the fano/window union)
    float inv = 1.f / lsum;
    ushort_t* op = Ab + (size_t)i * D_MODEL + cbase;
#pragma unroll
    for (int v4 = 0; v4 < 4; v4++) {
        uint4 u;
        u.x = f2bf(acc[v4 * 8 + 0] * inv) | (f2bf(acc[v4 * 8 + 1] * inv) << 16);
        u.y = f2bf(acc[v4 * 8 + 2] * inv) | (f2bf(acc[v4 * 8 + 3] * inv) << 16);
        u.z = f2bf(acc[v4 * 8 + 4] * inv) | (f2bf(acc[v4 * 8 + 5] * inv) << 16);
        u.w = f2bf(acc[v4 * 8 + 6] * inv) | (f2bf(acc[v4 * 8 + 7] * inv) << 16);
        *(uint4*)(op + v4 * 8) = u;
    }
}

extern "C" void kernel_launch(void* const* d_in, const int* in_sizes, int n_in,
                              void* d_out, int out_size, void* d_ws, size_t ws_size,
                              hipStream_t stream) {
    const void* x  = d_in[0];
    const void* Wq = d_in[1];
    const void* Wk = d_in[2];
    const void* Wv = d_in[3];
    const void* Wo = d_in[4];

    const size_t n = (size_t)T_SEQ * D_MODEL;
    int* flag = (int*)d_ws;
    ushort_t* Qb = (ushort_t*)d_ws + 128;   // 256B offset, keeps 16B alignment
    ushort_t* Kb = Qb + n;
    ushort_t* Vb = Kb + n;
    ushort_t* Ab = Vb + n;

    // 0: probe input dtype (1 = fp32, 0 = bf16)
    detect_dtype<<<1, 64, 0, stream>>>((const uint32_t*)x, flag);
    // 1: Q = x@Wq^T, K = x@Wk^T, V = x@Wv^T (fused via z); intermediates bf16
    gemm_nt<<<dim3(32, 7, 3), 256, 0, stream>>>(x, Wq, Wk, Wv, Qb, Kb, Vb,
                                                flag, 2, 2, 0);
    // 2: sparse attention -> Ab (bf16)
    fano_attn<<<dim3(64, 7), 256, 0, stream>>>(Qb, Kb, Vb, Ab);
    // 3: out = Ab@Wo^T (A bf16, B/C follow runtime dtype)
    gemm_nt<<<dim3(32, 7, 1), 256, 0, stream>>>(Ab, Wo, Wo, Wo, d_out, d_out, d_out,
                                                flag, 0, 2, 2);
}

// Round 3
// 296.527 us; speedup vs baseline: 4.5656x; 4.5656x over previous
//
#include <hip/hip_runtime.h>
#include <stdint.h>

typedef unsigned short ushort_t;
typedef __bf16 bf16x8 __attribute__((ext_vector_type(8)));
typedef float f32x4 __attribute__((ext_vector_type(4)));

#define T_SEQ 4096
#define D_MODEL 896

// LDS strides (u16 units). All 8-multiples (16B) for ds_read_b128 alignment.
// LSK=136: 68 dwords -> row advance 4 banks. LSV=LSP=104: 52 dwords -> 20-bank
// step (5-coprime spread).
#define LSK 136
#define LSV 104
#define LSP 104

// Fano lines, residues sorted ascending per head
__constant__ int d_LINEMASK[7] = {0x07, 0x19, 0x61, 0x2A, 0x52, 0x4C, 0x34};
__constant__ int d_R[7][3] = {{0,1,2},{0,3,4},{0,5,6},{1,3,5},{1,4,6},{2,3,6},{2,4,5}};

__device__ inline unsigned f2bf(float f) {
    unsigned x = __float_as_uint(f);
    return (x + 0x7fffu + ((x >> 16) & 1u)) >> 16;   // RNE
}

// ---------------------------------------------------------------------------
// Runtime dtype probe (unchanged from R2, verified): flag=1 -> fp32 inputs.
// ---------------------------------------------------------------------------
__global__ void detect_dtype(const uint32_t* __restrict__ x, int* __restrict__ flag) {
    const int lane = threadIdx.x;  // 64 threads, 1 wave
    int cnt = 0;
#pragma unroll
    for (int r = 0; r < 8; r++) {
        uint4 w = *(const uint4*)&x[(size_t)(r * 64 + lane) * 4];
        uint32_t v[4] = {w.x, w.y, w.z, w.w};
#pragma unroll
        for (int q = 0; q < 4; q++) {
            uint32_t lo = v[q] & 0xFFFFu;
            int e = (lo >> 7) & 0xFF;
            if (lo == 0u || (e >= 0x58 && e <= 0xA0)) cnt++;
        }
    }
#pragma unroll
    for (int o = 32; o > 0; o >>= 1) cnt += __shfl_down(cnt, o);
    if (lane == 0) flag[0] = (cnt < 1300) ? 1 : 0;
}

// stage 8 consecutive elements (bf16 passthrough or fp32->bf16) into LDS
__device__ inline void stage8(const void* P, bool is32, size_t off, ushort_t* dst) {
    if (is32) {
        const float* p = (const float*)P + off;
        float4 a = *(const float4*)p;
        float4 b = *(const float4*)(p + 4);
        uint4 u;
        u.x = f2bf(a.x) | (f2bf(a.y) << 16);
        u.y = f2bf(a.z) | (f2bf(a.w) << 16);
        u.z = f2bf(b.x) | (f2bf(b.y) << 16);
        u.w = f2bf(b.z) | (f2bf(b.w) << 16);
        *(uint4*)dst = u;
    } else {
        *(uint4*)dst = *(const uint4*)((const ushort_t*)P + off);
    }
}

// ---------------------------------------------------------------------------
// C[M,N] = A[M,K] @ B[N,K]^T  (fp32 acc). Unchanged from R2 (verified).
// ---------------------------------------------------------------------------
__global__ void gemm_nt(const void* __restrict__ A,
                        const void* __restrict__ B0,
                        const void* __restrict__ B1,
                        const void* __restrict__ B2,
                        void* __restrict__ C0,
                        void* __restrict__ C1,
                        void* __restrict__ C2,
                        const int* __restrict__ flag,
                        int amode, int bmode, int cmode) {
    const int z = blockIdx.z;
    const void* B = (z == 0) ? B0 : (z == 1) ? B1 : B2;
    void* C = (z == 0) ? C0 : (z == 1) ? C1 : C2;

    const int f = flag[0];
    const bool a32 = (amode == 2) ? (f != 0) : (amode == 1);
    const bool b32 = (bmode == 2) ? (f != 0) : (bmode == 1);
    const bool c32 = (cmode == 2) ? (f != 0) : (cmode == 1);

    const int K = D_MODEL, N = D_MODEL;
    const int i0 = blockIdx.x * 128;
    const int n0 = blockIdx.y * 128;

    __shared__ __align__(16) ushort_t As[128 * 32];
    __shared__ __align__(16) ushort_t Bs[128 * 32];

    const int t = threadIdx.x;
    const int w = t >> 6, l = t & 63;
    const int wm = (w >> 1) * 64, wn = (w & 1) * 64;
    const int lr = l & 15, lq = l >> 4;

    f32x4 acc[4][4];
#pragma unroll
    for (int a = 0; a < 4; a++)
#pragma unroll
        for (int b = 0; b < 4; b++) acc[a][b] = (f32x4){0.f, 0.f, 0.f, 0.f};

    for (int kt = 0; kt < K / 32; kt++) {
        const int k0 = kt * 32;
        __syncthreads();
#pragma unroll
        for (int rep = 0; rep < 2; rep++) {
            int q = t + rep * 256;
            int row = q >> 2, c16 = (q & 3) * 8;
            stage8(A, a32, (size_t)(i0 + row) * K + k0 + c16, &As[row * 32 + c16]);
            stage8(B, b32, (size_t)(n0 + row) * K + k0 + c16, &Bs[row * 32 + c16]);
        }
        __syncthreads();

        bf16x8 af[4], bfr[4];
#pragma unroll
        for (int mi = 0; mi < 4; mi++)
            af[mi] = *(const bf16x8*)&As[(wm + mi * 16 + lr) * 32 + lq * 8];
#pragma unroll
        for (int ni = 0; ni < 4; ni++)
            bfr[ni] = *(const bf16x8*)&Bs[(wn + ni * 16 + lr) * 32 + lq * 8];
#pragma unroll
        for (int mi = 0; mi < 4; mi++)
#pragma unroll
            for (int ni = 0; ni < 4; ni++)
                acc[mi][ni] = __builtin_amdgcn_mfma_f32_16x16x32_bf16(
                    af[mi], bfr[ni], acc[mi][ni], 0, 0, 0);
    }

    if (c32) {
        float* Cf = (float*)C;
#pragma unroll
        for (int mi = 0; mi < 4; mi++)
#pragma unroll
            for (int ni = 0; ni < 4; ni++)
#pragma unroll
                for (int r = 0; r < 4; r++) {
                    int row = i0 + wm + mi * 16 + lq * 4 + r;
                    int col = n0 + wn + ni * 16 + lr;
                    Cf[(size_t)row * N + col] = acc[mi][ni][r];
                }
    } else {
        ushort_t* Cb = (ushort_t*)C;
#pragma unroll
        for (int mi = 0; mi < 4; mi++)
#pragma unroll
            for (int ni = 0; ni < 4; ni++)
#pragma unroll
                for (int r = 0; r < 4; r++) {
                    int row = i0 + wm + mi * 16 + lq * 4 + r;
                    int col = n0 + wn + ni * 16 + lr;
                    Cb[(size_t)row * N + col] = (ushort_t)f2bf(acc[mi][ni][r]);
                }
    }
}

// scatter 8 dims of one key's V into Vt[d][key] (stride LSV); lane=key mapping
// across the wave hits all 32 banks -> conflict-free.
__device__ inline void vt_scatter8(ushort_t* vtcol, uint4 vv) {
    vtcol[0 * LSV] = (ushort_t)(vv.x & 0xFFFFu);
    vtcol[1 * LSV] = (ushort_t)(vv.x >> 16);
    vtcol[2 * LSV] = (ushort_t)(vv.y & 0xFFFFu);
    vtcol[3 * LSV] = (ushort_t)(vv.y >> 16);
    vtcol[4 * LSV] = (ushort_t)(vv.z & 0xFFFFu);
    vtcol[5 * LSV] = (ushort_t)(vv.z >> 16);
    vtcol[6 * LSV] = (ushort_t)(vv.w & 0xFFFFu);
    vtcol[7 * LSV] = (ushort_t)(vv.w >> 16);
}

// stage NV*8 dims of key j (row kk) into Ks (row-major) and Vt (transposed).
// j out of range -> zeros (prevents NaN/Inf garbage reaching MFMA).
template <int NV>
__device__ inline void stage_kv(const ushort_t* __restrict__ Kb,
                                const ushort_t* __restrict__ Vb,
                                ushort_t* Ks, ushort_t* Vt,
                                int j, int kk, int dim0, int h, bool ksw) {
    if (j >= 0 && j < T_SEQ) {
        const ushort_t* kp = Kb + (size_t)j * D_MODEL + h * 128 + dim0;
        const ushort_t* vp = Vb + (size_t)j * D_MODEL + h * 128 + dim0;
#pragma unroll
        for (int v = 0; v < NV; v++) {
            if (ksw) *(uint4*)&Ks[kk * LSK + dim0 + v * 8] = *(const uint4*)(kp + v * 8);
            vt_scatter8(&Vt[(dim0 + v * 8) * LSV + kk], *(const uint4*)(vp + v * 8));
        }
    } else {
        uint4 z = {0u, 0u, 0u, 0u};
#pragma unroll
        for (int v = 0; v < NV; v++) {
            if (ksw) *(uint4*)&Ks[kk * LSK + dim0 + v * 8] = z;
            vt_scatter8(&Vt[(dim0 + v * 8) * LSV + kk], z);
        }
    }
}

// ---------------------------------------------------------------------------
// MFMA Fano attention. Grid (64, 7) REVERSED in x (big blocks dispatch first).
// Block = (head, 64 query rows); wave = 16 rows. Chunks of 64 compacted keys
// (j = 7*(p/3)+r[p%3]) + one 80-key dense band for the local window.
// S: mfma(Q-Afrag, K-Bfrag) -> C-layout; online softmax per row (quad,reg);
// P -> bf16 -> Ps (LDS round-trip, m120 pattern) -> A-frag; PV: mfma(P, Vt).
// ---------------------------------------------------------------------------
__global__ __launch_bounds__(256)
void fano_attn_mfma(const ushort_t* __restrict__ Qb,
                    const ushort_t* __restrict__ Kb,
                    const ushort_t* __restrict__ Vb,
                    ushort_t* __restrict__ Ab) {
    const int h = blockIdx.y;
    const int tile = (int)gridDim.x - 1 - (int)blockIdx.x;  // LPT: big rows first
    const int i0 = tile * 64;
    const int t = threadIdx.x;
    const int w = t >> 6, lane = t & 63;
    const int lr = lane & 15, quad = lane >> 4;
    const int iw0 = i0 + w * 16;

    __shared__ __align__(16) ushort_t Ks[80 * LSK];   // 21760 B
    __shared__ __align__(16) ushort_t Vt[128 * LSV];  // 26624 B
    __shared__ __align__(16) ushort_t Ps[64 * LSP];   // 13312 B  (16 rows/wave)

    const int lm = d_LINEMASK[h];
    const int r0 = d_R[h][0], r1 = d_R[h][1], r2 = d_R[h][2];
    const float scale = 0.08838834764831845f;

    // Q A-frags: lane holds Q[iw0+lr][f*32 + quad*8 + (0..7)]
    bf16x8 qf[4];
    {
        const ushort_t* qrow = Qb + (size_t)(iw0 + lr) * D_MODEL + h * 128;
#pragma unroll
        for (int f = 0; f < 4; f++)
            qf[f] = *(const bf16x8*)(qrow + f * 32 + quad * 8);
    }

    f32x4 O[8];
#pragma unroll
    for (int dt = 0; dt < 8; dt++) O[dt] = (f32x4){0.f, 0.f, 0.f, 0.f};
    float m[4] = {-1e30f, -1e30f, -1e30f, -1e30f};
    float l[4] = {0.f, 0.f, 0.f, 0.f};

    // ================= band chunk: 80 keys j in [i0-16, i0+63] ==============
    const int wbase = i0 - 16;
    // stage phase 1: keys 0..63 (lane=key, wave=dim-group of 32)
    stage_kv<4>(Kb, Vb, Ks, Vt, wbase + lane, lane, w * 32, h, true);
    // stage phase 2: keys 64..95 (Ks only for <80; Vt cols 64..95 all valid/zero)
    {
        int kk2 = 64 + (lane & 31);
        int cg2 = w * 2 + (lane >> 5);
        stage_kv<2>(Kb, Vb, Ks, Vt, wbase + kk2, kk2, cg2 * 16, h, kk2 < 80);
    }
    __syncthreads();

    {   // band compute: per wave only tiles {w, w+1} are window-relevant
        const int tnA = w, tnB = w + 1;
        const int glo = w >> 1, ghi = (w + 1) >> 1;
        f32x4 S[2];
        S[0] = (f32x4){0.f, 0.f, 0.f, 0.f};
        S[1] = (f32x4){0.f, 0.f, 0.f, 0.f};
#pragma unroll
        for (int f = 0; f < 4; f++) {
            bf16x8 kfA = *(const bf16x8*)&Ks[(tnA * 16 + lr) * LSK + f * 32 + quad * 8];
            bf16x8 kfB = *(const bf16x8*)&Ks[(tnB * 16 + lr) * LSK + f * 32 + quad * 8];
            S[0] = __builtin_amdgcn_mfma_f32_16x16x32_bf16(qf[f], kfA, S[0], 0, 0, 0);
            S[1] = __builtin_amdgcn_mfma_f32_16x16x32_bf16(qf[f], kfB, S[1], 0, 0, 0);
        }
        const int jA = wbase + tnA * 16 + lr;
        const int jB = wbase + tnB * 16 + lr;
        const bool okA = (jA >= 0) && !((lm >> (((jA % 7) + 7) % 7)) & 1);
        const bool okB = (jB >= 0) && !((lm >> (((jB % 7) + 7) % 7)) & 1);
#pragma unroll
        for (int r = 0; r < 4; r++) {
            int ir = iw0 + quad * 4 + r;
            S[0][r] = (okA && jA <= ir && jA >= ir - 16) ? S[0][r] * scale : -1e30f;
            S[1][r] = (okB && jB <= ir && jB >= ir - 16) ? S[1][r] * scale : -1e30f;
        }
        float a4[4], p0[4], p1[4];
#pragma unroll
        for (int r = 0; r < 4; r++) {
            float cm = fmaxf(S[0][r], S[1][r]);
            cm = fmaxf(cm, __shfl_xor(cm, 1));
            cm = fmaxf(cm, __shfl_xor(cm, 2));
            cm = fmaxf(cm, __shfl_xor(cm, 4));
            cm = fmaxf(cm, __shfl_xor(cm, 8));
            float mn = fmaxf(m[r], cm);
            a4[r] = __expf(m[r] - mn);
            m[r] = mn;
            p0[r] = __expf(S[0][r] - mn);
            p1[r] = __expf(S[1][r] - mn);
            float rs_ = p0[r] + p1[r];
            rs_ += __shfl_xor(rs_, 1);
            rs_ += __shfl_xor(rs_, 2);
            rs_ += __shfl_xor(rs_, 4);
            rs_ += __shfl_xor(rs_, 8);
            l[r] = l[r] * a4[r] + rs_;
            // write P for tiles [2*glo, 2*ghi+1]; non-computed tiles -> 0
            ushort_t* pp = &Ps[(w * 16 + quad * 4 + r) * LSP + lr];
            for (int tz = 2 * glo; tz <= 2 * ghi + 1; tz++) {
                float pv = (tz == tnA) ? p0[r] : (tz == tnB) ? p1[r] : 0.f;
                pp[tz * 16] = (ushort_t)f2bf(pv);
            }
        }
#pragma unroll
        for (int dt = 0; dt < 8; dt++)
#pragma unroll
            for (int r = 0; r < 4; r++) O[dt][r] *= a4[r];
        for (int g = glo; g <= ghi; g++) {
            bf16x8 pf = *(const bf16x8*)&Ps[(w * 16 + lr) * LSP + g * 32 + quad * 8];
#pragma unroll
            for (int dt = 0; dt < 8; dt++) {
                bf16x8 vf = *(const bf16x8*)&Vt[(dt * 16 + lr) * LSV + g * 32 + quad * 8];
                O[dt] = __builtin_amdgcn_mfma_f32_16x16x32_bf16(pf, vf, O[dt], 0, 0, 0);
            }
        }
    }

    // ================= compacted Fano chunks: 64 keys each ==================
    const int imax = i0 + 63;
    const int ncomp = (imax - r0) / 7 + (imax - r1) / 7 + (imax - r2) / 7 + 3;
    const int nch = (ncomp + 63) >> 6;

    for (int cc = 0; cc < nch; cc++) {
        const int base = cc * 64;
        __syncthreads();
        {
            int p = base + lane;
            int g = p / 3, rs2 = p - 3 * g;
            int j = 7 * g + ((rs2 == 0) ? r0 : (rs2 == 1) ? r1 : r2);
            stage_kv<4>(Kb, Vb, Ks, Vt, j, lane, w * 32, h, true);
        }
        __syncthreads();

        // wave-uniform skip: chunk min j beyond this wave's rows
        {
            int gb = base / 3, rb = base - 3 * gb;
            int jmin = 7 * gb + ((rb == 0) ? r0 : (rb == 1) ? r1 : r2);
            if (jmin > iw0 + 15) continue;
        }

        f32x4 S[4];
#pragma unroll
        for (int tn = 0; tn < 4; tn++) S[tn] = (f32x4){0.f, 0.f, 0.f, 0.f};
#pragma unroll
        for (int f = 0; f < 4; f++) {
            bf16x8 kf[4];
#pragma unroll
            for (int tn = 0; tn < 4; tn++)
                kf[tn] = *(const bf16x8*)&Ks[(tn * 16 + lr) * LSK + f * 32 + quad * 8];
#pragma unroll
            for (int tn = 0; tn < 4; tn++)
                S[tn] = __builtin_amdgcn_mfma_f32_16x16x32_bf16(qf[f], kf[tn], S[tn], 0, 0, 0);
        }
        int jt[4];
#pragma unroll
        for (int tn = 0; tn < 4; tn++) {
            int p = base + tn * 16 + lr;
            int g = p / 3, rs2 = p - 3 * g;
            jt[tn] = 7 * g + ((rs2 == 0) ? r0 : (rs2 == 1) ? r1 : r2);
        }
#pragma unroll
        for (int tn = 0; tn < 4; tn++)
#pragma unroll
            for (int r = 0; r < 4; r++)
                S[tn][r] = (jt[tn] <= iw0 + quad * 4 + r) ? S[tn][r] * scale : -1e30f;

        float a4[4], pv[4][4];
#pragma unroll
        for (int r = 0; r < 4; r++) {
            float cm = fmaxf(fmaxf(S[0][r], S[1][r]), fmaxf(S[2][r], S[3][r]));
            cm = fmaxf(cm, __shfl_xor(cm, 1));
            cm = fmaxf(cm, __shfl_xor(cm, 2));
            cm = fmaxf(cm, __shfl_xor(cm, 4));
            cm = fmaxf(cm, __shfl_xor(cm, 8));
            float mn = fmaxf(m[r], cm);
            a4[r] = __expf(m[r] - mn);
            m[r] = mn;
            float rs_ = 0.f;
#pragma unroll
            for (int tn = 0; tn < 4; tn++) {
                pv[tn][r] = __expf(S[tn][r] - mn);
                rs_ += pv[tn][r];
            }
            rs_ += __shfl_xor(rs_, 1);
            rs_ += __shfl_xor(rs_, 2);
            rs_ += __shfl_xor(rs_, 4);
            rs_ += __shfl_xor(rs_, 8);
            l[r] = l[r] * a4[r] + rs_;
            ushort_t* pp = &Ps[(w * 16 + quad * 4 + r) * LSP + lr];
            pp[0]  = (ushort_t)f2bf(pv[0][r]);
            pp[16] = (ushort_t)f2bf(pv[1][r]);
            pp[32] = (ushort_t)f2bf(pv[2][r]);
            pp[48] = (ushort_t)f2bf(pv[3][r]);
        }
#pragma unroll
        for (int dt = 0; dt < 8; dt++)
#pragma unroll
            for (int r = 0; r < 4; r++) O[dt][r] *= a4[r];

        bf16x8 pf0 = *(const bf16x8*)&Ps[(w * 16 + lr) * LSP + quad * 8];
        bf16x8 pf1 = *(const bf16x8*)&Ps[(w * 16 + lr) * LSP + 32 + quad * 8];
#pragma unroll
        for (int dt = 0; dt < 8; dt++) {
            bf16x8 v0 = *(const bf16x8*)&Vt[(dt * 16 + lr) * LSV + quad * 8];
            bf16x8 v1 = *(const bf16x8*)&Vt[(dt * 16 + lr) * LSV + 32 + quad * 8];
            O[dt] = __builtin_amdgcn_mfma_f32_16x16x32_bf16(pf0, v0, O[dt], 0, 0, 0);
            O[dt] = __builtin_amdgcn_mfma_f32_16x16x32_bf16(pf1, v1, O[dt], 0, 0, 0);
        }
    }

    // ================= finalize =================
    float inv[4];
#pragma unroll
    for (int r = 0; r < 4; r++) inv[r] = 1.f / l[r];
#pragma unroll
    for (int dt = 0; dt < 8; dt++)
#pragma unroll
        for (int r = 0; r < 4; r++) {
            int row = iw0 + quad * 4 + r;
            int col = h * 128 + dt * 16 + lr;
            Ab[(size_t)row * D_MODEL + col] = (ushort_t)f2bf(O[dt][r] * inv[r]);
        }
}

extern "C" void kernel_launch(void* const* d_in, const int* in_sizes, int n_in,
                              void* d_out, int out_size, void* d_ws, size_t ws_size,
                              hipStream_t stream) {
    const void* x  = d_in[0];
    const void* Wq = d_in[1];
    const void* Wk = d_in[2];
    const void* Wv = d_in[3];
    const void* Wo = d_in[4];

    const size_t n = (size_t)T_SEQ * D_MODEL;
    int* flag = (int*)d_ws;
    ushort_t* Qb = (ushort_t*)d_ws + 128;   // 256B offset, keeps 16B alignment
    ushort_t* Kb = Qb + n;
    ushort_t* Vb = Kb + n;
    ushort_t* Ab = Vb + n;

    detect_dtype<<<1, 64, 0, stream>>>((const uint32_t*)x, flag);
    gemm_nt<<<dim3(32, 7, 3), 256, 0, stream>>>(x, Wq, Wk, Wv, Qb, Kb, Vb,
                                                flag, 2, 2, 0);
    fano_attn_mfma<<<dim3(64, 7), 256, 0, stream>>>(Qb, Kb, Vb, Ab);
    gemm_nt<<<dim3(32, 7, 1), 256, 0, stream>>>(Ab, Wo, Wo, Wo, d_out, d_out, d_out,
                                                flag, 0, 2, 2);
}

// Round 8
// 254.135 us; speedup vs baseline: 5.3272x; 1.1668x over previous
//
#include <hip/hip_runtime.h>
#include <stdint.h>

typedef unsigned short ushort_t;
typedef __bf16 bf16x8 __attribute__((ext_vector_type(8)));
typedef float f32x4 __attribute__((ext_vector_type(4)));

#define T_SEQ 4096
#define D_MODEL 896

// R3-VERIFIED attention LDS strides (u16 units, 8-multiples for b128 align).
#define LSK 136
#define LSV 104
#define LSP 104

// Fano lines, residues sorted ascending per head
__constant__ int d_LINEMASK[7] = {0x07, 0x19, 0x61, 0x2A, 0x52, 0x4C, 0x34};
__constant__ int d_R[7][3] = {{0,1,2},{0,3,4},{0,5,6},{1,3,5},{1,4,6},{2,3,6},{2,4,5}};

__device__ inline unsigned f2bf(float f) {
    unsigned x = __float_as_uint(f);
    return (x + 0x7fffu + ((x >> 16) & 1u)) >> 16;   // RNE
}

// stage 8 consecutive elements into LDS: fp32 source -> convert to bf16;
// bf16 source -> passthrough. (R2/R3-verified stage8, dtype now compile-time.)
template <bool IS32>
__device__ inline void stage8(const void* P, size_t off, ushort_t* dst) {
    if (IS32) {
        const float* p = (const float*)P + off;
        float4 a = *(const float4*)p;
        float4 b = *(const float4*)(p + 4);
        uint4 u;
        u.x = f2bf(a.x) | (f2bf(a.y) << 16);
        u.y = f2bf(a.z) | (f2bf(a.w) << 16);
        u.z = f2bf(b.x) | (f2bf(b.y) << 16);
        u.w = f2bf(b.z) | (f2bf(b.w) << 16);
        *(uint4*)dst = u;
    } else {
        *(uint4*)dst = *(const uint4*)((const ushort_t*)P + off);
    }
}

// ---------------------------------------------------------------------------
// C[M,N] = A[M,K] @ B[N,K]^T (fp32 acc). M=4096, N=K=896. R2/R3-VERIFIED
// structure: 128x128 tile, BK=32, 4 waves (2x2 of 64x64), VGPR-staged LDS.
// INPUTS/OUTPUT ARE FP32 (reference dtype); intermediates bf16.
// A32/B32/C32 select fp32 (true) vs bf16 (false) per tensor at compile time.
// blockIdx.z selects (B, C) pair -> fuses Q/K/V projections.
// ---------------------------------------------------------------------------
template <bool A32, bool B32, bool C32>
__global__ __launch_bounds__(256)
void gemm_nt(const void* __restrict__ A,
             const void* __restrict__ B0,
             const void* __restrict__ B1,
             const void* __restrict__ B2,
             void* __restrict__ C0,
             void* __restrict__ C1,
             void* __restrict__ C2) {
    const int z = blockIdx.z;
    const void* B = (z == 0) ? B0 : (z == 1) ? B1 : B2;
    void* C = (z == 0) ? C0 : (z == 1) ? C1 : C2;

    const int K = D_MODEL, N = D_MODEL;
    const int i0 = blockIdx.x * 128;
    const int n0 = blockIdx.y * 128;

    __shared__ __align__(16) ushort_t As[128 * 32];
    __shared__ __align__(16) ushort_t Bs[128 * 32];

    const int t = threadIdx.x;
    const int w = t >> 6, l = t & 63;
    const int wm = (w >> 1) * 64, wn = (w & 1) * 64;
    const int lr = l & 15, lq = l >> 4;

    f32x4 acc[4][4];
#pragma unroll
    for (int a = 0; a < 4; a++)
#pragma unroll
        for (int b = 0; b < 4; b++) acc[a][b] = (f32x4){0.f, 0.f, 0.f, 0.f};

    for (int kt = 0; kt < K / 32; kt++) {
        const int k0 = kt * 32;
        __syncthreads();
#pragma unroll
        for (int rep = 0; rep < 2; rep++) {
            int q = t + rep * 256;
            int row = q >> 2, c16 = (q & 3) * 8;
            stage8<A32>(A, (size_t)(i0 + row) * K + k0 + c16, &As[row * 32 + c16]);
            stage8<B32>(B, (size_t)(n0 + row) * K + k0 + c16, &Bs[row * 32 + c16]);
        }
        __syncthreads();

        bf16x8 af[4], bfr[4];
#pragma unroll
        for (int mi = 0; mi < 4; mi++)
            af[mi] = *(const bf16x8*)&As[(wm + mi * 16 + lr) * 32 + lq * 8];
#pragma unroll
        for (int ni = 0; ni < 4; ni++)
            bfr[ni] = *(const bf16x8*)&Bs[(wn + ni * 16 + lr) * 32 + lq * 8];
#pragma unroll
        for (int mi = 0; mi < 4; mi++)
#pragma unroll
            for (int ni = 0; ni < 4; ni++)
                acc[mi][ni] = __builtin_amdgcn_mfma_f32_16x16x32_bf16(
                    af[mi], bfr[ni], acc[mi][ni], 0, 0, 0);
    }

    // C/D layout: col = lane&15, row = (lane>>4)*4 + reg
    if (C32) {
        float* Cf = (float*)C;
#pragma unroll
        for (int mi = 0; mi < 4; mi++)
#pragma unroll
            for (int ni = 0; ni < 4; ni++)
#pragma unroll
                for (int r = 0; r < 4; r++) {
                    int row = i0 + wm + mi * 16 + lq * 4 + r;
                    int col = n0 + wn + ni * 16 + lr;
                    Cf[(size_t)row * N + col] = acc[mi][ni][r];
                }
    } else {
        ushort_t* Cb = (ushort_t*)C;
#pragma unroll
        for (int mi = 0; mi < 4; mi++)
#pragma unroll
            for (int ni = 0; ni < 4; ni++)
#pragma unroll
                for (int r = 0; r < 4; r++) {
                    int row = i0 + wm + mi * 16 + lq * 4 + r;
                    int col = n0 + wn + ni * 16 + lr;
                    Cb[(size_t)row * N + col] = (ushort_t)f2bf(acc[mi][ni][r]);
                }
    }
}

// scatter 8 dims of one key's V into Vt[d][key] (stride LSV); lane=key mapping
__device__ inline void vt_scatter8(ushort_t* vtcol, uint4 vv) {
    vtcol[0 * LSV] = (ushort_t)(vv.x & 0xFFFFu);
    vtcol[1 * LSV] = (ushort_t)(vv.x >> 16);
    vtcol[2 * LSV] = (ushort_t)(vv.y & 0xFFFFu);
    vtcol[3 * LSV] = (ushort_t)(vv.y >> 16);
    vtcol[4 * LSV] = (ushort_t)(vv.z & 0xFFFFu);
    vtcol[5 * LSV] = (ushort_t)(vv.z >> 16);
    vtcol[6 * LSV] = (ushort_t)(vv.w & 0xFFFFu);
    vtcol[7 * LSV] = (ushort_t)(vv.w >> 16);
}

// stage NV*8 dims of key j (row kk) into Ks (row-major) and Vt (transposed).
// j out of range -> zeros (prevents NaN/Inf garbage reaching MFMA).
template <int NV>
__device__ inline void stage_kv(const ushort_t* __restrict__ Kb,
                                const ushort_t* __restrict__ Vb,
                                ushort_t* Ks, ushort_t* Vt,
                                int j, int kk, int dim0, int h, bool ksw) {
    if (j >= 0 && j < T_SEQ) {
        const ushort_t* kp = Kb + (size_t)j * D_MODEL + h * 128 + dim0;
        const ushort_t* vp = Vb + (size_t)j * D_MODEL + h * 128 + dim0;
#pragma unroll
        for (int v = 0; v < NV; v++) {
            if (ksw) *(uint4*)&Ks[kk * LSK + dim0 + v * 8] = *(const uint4*)(kp + v * 8);
            vt_scatter8(&Vt[(dim0 + v * 8) * LSV + kk], *(const uint4*)(vp + v * 8));
        }
    } else {
        uint4 z = {0u, 0u, 0u, 0u};
#pragma unroll
        for (int v = 0; v < NV; v++) {
            if (ksw) *(uint4*)&Ks[kk * LSK + dim0 + v * 8] = z;
            vt_scatter8(&Vt[(dim0 + v * 8) * LSV + kk], z);
        }
    }
}

// ---------------------------------------------------------------------------
// MFMA Fano attention — EXACT R3 version (bf16 intermediates in/out).
// Grid (64, 7), x-reversed (LPT). Block = (head, 64 q-rows); wave = 16 rows.
// One 80-key band chunk first, then fano-compacted 64-key chunks.
// ---------------------------------------------------------------------------
__global__ __launch_bounds__(256)
void fano_attn_mfma(const ushort_t* __restrict__ Qb,
                    const ushort_t* __restrict__ Kb,
                    const ushort_t* __restrict__ Vb,
                    ushort_t* __restrict__ Ab) {
    const int h = blockIdx.y;
    const int tile = (int)gridDim.x - 1 - (int)blockIdx.x;  // LPT: big rows first
    const int i0 = tile * 64;
    const int t = threadIdx.x;
    const int w = t >> 6, lane = t & 63;
    const int lr = lane & 15, quad = lane >> 4;
    const int iw0 = i0 + w * 16;

    __shared__ __align__(16) ushort_t Ks[80 * LSK];   // 21760 B
    __shared__ __align__(16) ushort_t Vt[128 * LSV];  // 26624 B
    __shared__ __align__(16) ushort_t Ps[64 * LSP];   // 13312 B

    const int lm = d_LINEMASK[h];
    const int r0 = d_R[h][0], r1 = d_R[h][1], r2 = d_R[h][2];
    const float scale = 0.08838834764831845f;

    // Q A-frags: lane holds Q[iw0+lr][f*32 + quad*8 + (0..7)]
    bf16x8 qf[4];
    {
        const ushort_t* qrow = Qb + (size_t)(iw0 + lr) * D_MODEL + h * 128;
#pragma unroll
        for (int f = 0; f < 4; f++)
            qf[f] = *(const bf16x8*)(qrow + f * 32 + quad * 8);
    }

    f32x4 O[8];
#pragma unroll
    for (int dt = 0; dt < 8; dt++) O[dt] = (f32x4){0.f, 0.f, 0.f, 0.f};
    float m[4] = {-1e30f, -1e30f, -1e30f, -1e30f};
    float l[4] = {0.f, 0.f, 0.f, 0.f};

    // ================= band chunk: 80 keys j in [i0-16, i0+63] ==============
    const int wbase = i0 - 16;
    stage_kv<4>(Kb, Vb, Ks, Vt, wbase + lane, lane, w * 32, h, true);
    {
        int kk2 = 64 + (lane & 31);
        int cg2 = w * 2 + (lane >> 5);
        stage_kv<2>(Kb, Vb, Ks, Vt, wbase + kk2, kk2, cg2 * 16, h, kk2 < 80);
    }
    __syncthreads();

    {   // band compute: per wave only tiles {w, w+1} are window-relevant
        const int tnA = w, tnB = w + 1;
        const int glo = w >> 1, ghi = (w + 1) >> 1;
        f32x4 S[2];
        S[0] = (f32x4){0.f, 0.f, 0.f, 0.f};
        S[1] = (f32x4){0.f, 0.f, 0.f, 0.f};
#pragma unroll
        for (int f = 0; f < 4; f++) {
            bf16x8 kfA = *(const bf16x8*)&Ks[(tnA * 16 + lr) * LSK + f * 32 + quad * 8];
            bf16x8 kfB = *(const bf16x8*)&Ks[(tnB * 16 + lr) * LSK + f * 32 + quad * 8];
            S[0] = __builtin_amdgcn_mfma_f32_16x16x32_bf16(qf[f], kfA, S[0], 0, 0, 0);
            S[1] = __builtin_amdgcn_mfma_f32_16x16x32_bf16(qf[f], kfB, S[1], 0, 0, 0);
        }
        const int jA = wbase + tnA * 16 + lr;
        const int jB = wbase + tnB * 16 + lr;
        const bool okA = (jA >= 0) && !((lm >> (((jA % 7) + 7) % 7)) & 1);
        const bool okB = (jB >= 0) && !((lm >> (((jB % 7) + 7) % 7)) & 1);
#pragma unroll
        for (int r = 0; r < 4; r++) {
            int ir = iw0 + quad * 4 + r;
            S[0][r] = (okA && jA <= ir && jA >= ir - 16) ? S[0][r] * scale : -1e30f;
            S[1][r] = (okB && jB <= ir && jB >= ir - 16) ? S[1][r] * scale : -1e30f;
        }
        float a4[4], p0[4], p1[4];
#pragma unroll
        for (int r = 0; r < 4; r++) {
            float cm = fmaxf(S[0][r], S[1][r]);
            cm = fmaxf(cm, __shfl_xor(cm, 1));
            cm = fmaxf(cm, __shfl_xor(cm, 2));
            cm = fmaxf(cm, __shfl_xor(cm, 4));
            cm = fmaxf(cm, __shfl_xor(cm, 8));
            float mn = fmaxf(m[r], cm);
            a4[r] = __expf(m[r] - mn);
            m[r] = mn;
            p0[r] = __expf(S[0][r] - mn);
            p1[r] = __expf(S[1][r] - mn);
            float rs_ = p0[r] + p1[r];
            rs_ += __shfl_xor(rs_, 1);
            rs_ += __shfl_xor(rs_, 2);
            rs_ += __shfl_xor(rs_, 4);
            rs_ += __shfl_xor(rs_, 8);
            l[r] = l[r] * a4[r] + rs_;
            ushort_t* pp = &Ps[(w * 16 + quad * 4 + r) * LSP + lr];
            for (int tz = 2 * glo; tz <= 2 * ghi + 1; tz++) {
                float pv = (tz == tnA) ? p0[r] : (tz == tnB) ? p1[r] : 0.f;
                pp[tz * 16] = (ushort_t)f2bf(pv);
            }
        }
#pragma unroll
        for (int dt = 0; dt < 8; dt++)
#pragma unroll
            for (int r = 0; r < 4; r++) O[dt][r] *= a4[r];
        for (int g = glo; g <= ghi; g++) {
            bf16x8 pf = *(const bf16x8*)&Ps[(w * 16 + lr) * LSP + g * 32 + quad * 8];
#pragma unroll
            for (int dt = 0; dt < 8; dt++) {
                bf16x8 vf = *(const bf16x8*)&Vt[(dt * 16 + lr) * LSV + g * 32 + quad * 8];
                O[dt] = __builtin_amdgcn_mfma_f32_16x16x32_bf16(pf, vf, O[dt], 0, 0, 0);
            }
        }
    }

    // ================= compacted Fano chunks: 64 keys each ==================
    const int imax = i0 + 63;
    const int ncomp = (imax - r0) / 7 + (imax - r1) / 7 + (imax - r2) / 7 + 3;
    const int nch = (ncomp + 63) >> 6;

    for (int cc = 0; cc < nch; cc++) {
        const int base = cc * 64;
        __syncthreads();
        {
            int p = base + lane;
            int g = p / 3, rs2 = p - 3 * g;
            int j = 7 * g + ((rs2 == 0) ? r0 : (rs2 == 1) ? r1 : r2);
            stage_kv<4>(Kb, Vb, Ks, Vt, j, lane, w * 32, h, true);
        }
        __syncthreads();

        // wave-uniform skip: chunk min j beyond this wave's rows
        {
            int gb = base / 3, rb = base - 3 * gb;
            int jmin = 7 * gb + ((rb == 0) ? r0 : (rb == 1) ? r1 : r2);
            if (jmin > iw0 + 15) continue;
        }

        f32x4 S[4];
#pragma unroll
        for (int tn = 0; tn < 4; tn++) S[tn] = (f32x4){0.f, 0.f, 0.f, 0.f};
#pragma unroll
        for (int f = 0; f < 4; f++) {
            bf16x8 kf[4];
#pragma unroll
            for (int tn = 0; tn < 4; tn++)
                kf[tn] = *(const bf16x8*)&Ks[(tn * 16 + lr) * LSK + f * 32 + quad * 8];
#pragma unroll
            for (int tn = 0; tn < 4; tn++)
                S[tn] = __builtin_amdgcn_mfma_f32_16x16x32_bf16(qf[f], kf[tn], S[tn], 0, 0, 0);
        }
        int jt[4];
#pragma unroll
        for (int tn = 0; tn < 4; tn++) {
            int p = base + tn * 16 + lr;
            int g = p / 3, rs2 = p - 3 * g;
            jt[tn] = 7 * g + ((rs2 == 0) ? r0 : (rs2 == 1) ? r1 : r2);
        }
#pragma unroll
        for (int tn = 0; tn < 4; tn++)
#pragma unroll
            for (int r = 0; r < 4; r++)
                S[tn][r] = (jt[tn] <= iw0 + quad * 4 + r) ? S[tn][r] * scale : -1e30f;

        float a4[4], pv[4][4];
#pragma unroll
        for (int r = 0; r < 4; r++) {
            float cm = fmaxf(fmaxf(S[0][r], S[1][r]), fmaxf(S[2][r], S[3][r]));
            cm = fmaxf(cm, __shfl_xor(cm, 1));
            cm = fmaxf(cm, __shfl_xor(cm, 2));
            cm = fmaxf(cm, __shfl_xor(cm, 4));
            cm = fmaxf(cm, __shfl_xor(cm, 8));
            float mn = fmaxf(m[r], cm);
            a4[r] = __expf(m[r] - mn);
            m[r] = mn;
            float rs_ = 0.f;
#pragma unroll
            for (int tn = 0; tn < 4; tn++) {
                pv[tn][r] = __expf(S[tn][r] - mn);
                rs_ += pv[tn][r];
            }
            rs_ += __shfl_xor(rs_, 1);
            rs_ += __shfl_xor(rs_, 2);
            rs_ += __shfl_xor(rs_, 4);
            rs_ += __shfl_xor(rs_, 8);
            l[r] = l[r] * a4[r] + rs_;
            ushort_t* pp = &Ps[(w * 16 + quad * 4 + r) * LSP + lr];
            pp[0]  = (ushort_t)f2bf(pv[0][r]);
            pp[16] = (ushort_t)f2bf(pv[1][r]);
            pp[32] = (ushort_t)f2bf(pv[2][r]);
            pp[48] = (ushort_t)f2bf(pv[3][r]);
        }
#pragma unroll
        for (int dt = 0; dt < 8; dt++)
#pragma unroll
            for (int r = 0; r < 4; r++) O[dt][r] *= a4[r];

        bf16x8 pf0 = *(const bf16x8*)&Ps[(w * 16 + lr) * LSP + quad * 8];
        bf16x8 pf1 = *(const bf16x8*)&Ps[(w * 16 + lr) * LSP + 32 + quad * 8];
#pragma unroll
        for (int dt = 0; dt < 8; dt++) {
            bf16x8 v0 = *(const bf16x8*)&Vt[(dt * 16 + lr) * LSV + quad * 8];
            bf16x8 v1 = *(const bf16x8*)&Vt[(dt * 16 + lr) * LSV + 32 + quad * 8];
            O[dt] = __builtin_amdgcn_mfma_f32_16x16x32_bf16(pf0, v0, O[dt], 0, 0, 0);
            O[dt] = __builtin_amdgcn_mfma_f32_16x16x32_bf16(pf1, v1, O[dt], 0, 0, 0);
        }
    }

    // ================= finalize =================
    float inv[4];
#pragma unroll
    for (int r = 0; r < 4; r++) inv[r] = 1.f / l[r];
#pragma unroll
    for (int dt = 0; dt < 8; dt++)
#pragma unroll
        for (int r = 0; r < 4; r++) {
            int row = iw0 + quad * 4 + r;
            int col = h * 128 + dt * 16 + lr;
            Ab[(size_t)row * D_MODEL + col] = (ushort_t)f2bf(O[dt][r] * inv[r]);
        }
}

extern "C" void kernel_launch(void* const* d_in, const int* in_sizes, int n_in,
                              void* d_out, int out_size, void* d_ws, size_t ws_size,
                              hipStream_t stream) {
    const void* x  = d_in[0];   // fp32 [4096, 896]
    const void* Wq = d_in[1];   // fp32 [896, 896]
    const void* Wk = d_in[2];
    const void* Wv = d_in[3];
    const void* Wo = d_in[4];

    const size_t n = (size_t)T_SEQ * D_MODEL;
    ushort_t* Qb = (ushort_t*)d_ws + 128;   // 256B offset (R2/R3 layout parity)
    ushort_t* Kb = Qb + n;
    ushort_t* Vb = Kb + n;
    ushort_t* Ab = Vb + n;

    // Q/K/V = x @ W^T : fp32 inputs -> bf16 intermediates
    gemm_nt<true, true, false><<<dim3(32, 7, 3), 256, 0, stream>>>(
        x, Wq, Wk, Wv, Qb, Kb, Vb);
    // sparse attention on bf16 intermediates
    fano_attn_mfma<<<dim3(64, 7), 256, 0, stream>>>(Qb, Kb, Vb, Ab);
    // out = Ab @ Wo^T : bf16 A, fp32 B -> fp32 output
    gemm_nt<false, true, true><<<dim3(32, 7, 1), 256, 0, stream>>>(
        Ab, Wo, Wo, Wo, d_out, d_out, d_out);
}

// Round 9
// 251.632 us; speedup vs baseline: 5.3802x; 1.0099x over previous
//
#include <hip/hip_runtime.h>
#include <stdint.h>

typedef unsigned short ushort_t;
typedef __bf16 bf16x8 __attribute__((ext_vector_type(8)));
typedef float f32x4 __attribute__((ext_vector_type(4)));

#define T_SEQ 4096
#define D_MODEL 896

// Attention LDS strides (u16 units, 8-multiples for ds_read_b128 alignment).
#define LSK 136   // 68 dwords/row
#define LSV 72    // 36 dwords/row; lane=key scatter spans all 32 banks (2-way)
#define LSP 72

// Fano lines, residues sorted ascending per head
__constant__ int d_LINEMASK[7] = {0x07, 0x19, 0x61, 0x2A, 0x52, 0x4C, 0x34};
__constant__ int d_R[7][3] = {{0,1,2},{0,3,4},{0,5,6},{1,3,5},{1,4,6},{2,3,6},{2,4,5}};

__device__ inline unsigned f2bf(float f) {
    unsigned x = __float_as_uint(f);
    return (x + 0x7fffu + ((x >> 16) & 1u)) >> 16;   // RNE
}

// ---------------------------------------------------------------------------
// fp32 -> bf16 bulk convert, 5 tensors (x, Wq, Wk, Wv, Wo). 8 elem/thread.
// ---------------------------------------------------------------------------
__global__ __launch_bounds__(256)
void cvt5(const float* __restrict__ x,  const float* __restrict__ wq,
          const float* __restrict__ wk, const float* __restrict__ wv,
          const float* __restrict__ wo,
          ushort_t* __restrict__ xb,  ushort_t* __restrict__ wqb,
          ushort_t* __restrict__ wkb, ushort_t* __restrict__ wvb,
          ushort_t* __restrict__ wob) {
    const int ten = blockIdx.y;
    const float* s = (ten == 0) ? x : (ten == 1) ? wq : (ten == 2) ? wk
                   : (ten == 3) ? wv : wo;
    ushort_t* d = (ten == 0) ? xb : (ten == 1) ? wqb : (ten == 2) ? wkb
                : (ten == 3) ? wvb : wob;
    const int n8 = ((ten == 0) ? T_SEQ * D_MODEL : D_MODEL * D_MODEL) >> 3;
    for (int i = blockIdx.x * 256 + threadIdx.x; i < n8; i += gridDim.x * 256) {
        float4 a = ((const float4*)s)[2 * i];
        float4 b = ((const float4*)s)[2 * i + 1];
        uint4 u;
        u.x = f2bf(a.x) | (f2bf(a.y) << 16);
        u.y = f2bf(a.z) | (f2bf(a.w) << 16);
        u.z = f2bf(b.x) | (f2bf(b.y) << 16);
        u.w = f2bf(b.z) | (f2bf(b.w) << 16);
        ((uint4*)d)[i] = u;
    }
}

// async global->LDS DMA, 16 B/lane. LDS dest = wave-uniform base + lane*16.
__device__ __forceinline__ void async_cp16(const void* g, void* l) {
    __builtin_amdgcn_global_load_lds(
        (__attribute__((address_space(1))) void*)g,
        (__attribute__((address_space(3))) void*)l,
        16, 0, 0);
}

// ---------------------------------------------------------------------------
// C[M,N] = A[M,K] @ B[N,K]^T, bf16 in, fp32 acc, bf16 or fp32 out.
// m97 structure: 128x128 tile, BK=32, 4 waves (2x2 of 64x64), staging via
// global_load_lds_dwordx4: wave w stages rows [w*16,w*16+16) of each 64-row
// half; lane i covers row i>>2, cols [(i&3)*8,+8) -> LDS off = lane*16 B.
// blockIdx.z selects (B, C) pair -> fuses Q/K/V projections.
// ---------------------------------------------------------------------------
template <bool C32>
__global__ __launch_bounds__(256)
void gemm_nt_dma(const ushort_t* __restrict__ A,
                 const ushort_t* __restrict__ B0,
                 const ushort_t* __restrict__ B1,
                 const ushort_t* __restrict__ B2,
                 void* __restrict__ C0,
                 void* __restrict__ C1,
                 void* __restrict__ C2) {
    const int z = blockIdx.z;
    const ushort_t* B = (z == 0) ? B0 : (z == 1) ? B1 : B2;
    void* C = (z == 0) ? C0 : (z == 1) ? C1 : C2;

    const int K = D_MODEL, N = D_MODEL;
    const int i0 = blockIdx.x * 128;
    const int n0 = blockIdx.y * 128;

    __shared__ __align__(16) ushort_t As[128 * 32];   // NO padding (DMA layout)
    __shared__ __align__(16) ushort_t Bs[128 * 32];

    const int t = threadIdx.x;
    const int w = t >> 6, lane = t & 63;
    const int wm = (w >> 1) * 64, wn = (w & 1) * 64;
    const int lr = lane & 15, lq = lane >> 4;

    const int srow = w * 16 + (lane >> 2);
    const int scol = (lane & 3) * 8;
    const ushort_t* gA0 = A + (size_t)(i0 + srow) * K + scol;
    const ushort_t* gA1 = A + (size_t)(i0 + 64 + srow) * K + scol;
    const ushort_t* gB0 = B + (size_t)(n0 + srow) * K + scol;
    const ushort_t* gB1 = B + (size_t)(n0 + 64 + srow) * K + scol;
    ushort_t* lA0 = &As[(w * 16) * 32];        // wave-uniform LDS bases
    ushort_t* lA1 = &As[(64 + w * 16) * 32];
    ushort_t* lB0 = &Bs[(w * 16) * 32];
    ushort_t* lB1 = &Bs[(64 + w * 16) * 32];

    f32x4 acc[4][4];
#pragma unroll
    for (int a = 0; a < 4; a++)
#pragma unroll
        for (int b = 0; b < 4; b++) acc[a][b] = (f32x4){0.f, 0.f, 0.f, 0.f};

    for (int k0 = 0; k0 < K; k0 += 32) {
        __syncthreads();
        async_cp16(gA0 + k0, lA0);
        async_cp16(gA1 + k0, lA1);
        async_cp16(gB0 + k0, lB0);
        async_cp16(gB1 + k0, lB1);
        __builtin_amdgcn_s_waitcnt(0);   // DMA landed in LDS
        __syncthreads();

        bf16x8 af[4], bfr[4];
#pragma unroll
        for (int mi = 0; mi < 4; mi++)
            af[mi] = *(const bf16x8*)&As[(wm + mi * 16 + lr) * 32 + lq * 8];
#pragma unroll
        for (int ni = 0; ni < 4; ni++)
            bfr[ni] = *(const bf16x8*)&Bs[(wn + ni * 16 + lr) * 32 + lq * 8];
#pragma unroll
        for (int mi = 0; mi < 4; mi++)
#pragma unroll
            for (int ni = 0; ni < 4; ni++)
                acc[mi][ni] = __builtin_amdgcn_mfma_f32_16x16x32_bf16(
                    af[mi], bfr[ni], acc[mi][ni], 0, 0, 0);
    }

    // C/D layout: col = lane&15, row = (lane>>4)*4 + reg
    if (C32) {
        float* Cf = (float*)C;
#pragma unroll
        for (int mi = 0; mi < 4; mi++)
#pragma unroll
            for (int ni = 0; ni < 4; ni++)
#pragma unroll
                for (int r = 0; r < 4; r++) {
                    int row = i0 + wm + mi * 16 + lq * 4 + r;
                    int col = n0 + wn + ni * 16 + lr;
                    Cf[(size_t)row * N + col] = acc[mi][ni][r];
                }
    } else {
        ushort_t* Cb = (ushort_t*)C;
#pragma unroll
        for (int mi = 0; mi < 4; mi++)
#pragma unroll
            for (int ni = 0; ni < 4; ni++)
#pragma unroll
                for (int r = 0; r < 4; r++) {
                    int row = i0 + wm + mi * 16 + lq * 4 + r;
                    int col = n0 + wn + ni * 16 + lr;
                    Cb[(size_t)row * N + col] = (ushort_t)f2bf(acc[mi][ni][r]);
                }
    }
}

// compacted-index -> key: p -> j = 7*(p/3) + r[p%3]
__device__ inline int jof(int p, int r0, int r1, int r2) {
    int g = p / 3, rs = p - 3 * g;
    return 7 * g + ((rs == 0) ? r0 : (rs == 1) ? r1 : r2);
}

// ---------------------------------------------------------------------------
// MFMA Fano attention + register software-pipeline. Grid (64,7) x-reversed.
// Block = (head, 64 q-rows); wave = 16 rows. Unified 64-key chunks: nch
// fano-compacted then 2 linear band chunks. Per chunk: publish prefetched
// K/V regs to LDS, issue next chunk's gather (overlaps compute), compute.
// LDS 44 KB -> 3 blocks/CU.
// ---------------------------------------------------------------------------
__global__ __launch_bounds__(256, 3)
void fano_attn_mfma(const ushort_t* __restrict__ Qb,
                    const ushort_t* __restrict__ Kb,
                    const ushort_t* __restrict__ Vb,
                    ushort_t* __restrict__ Ab) {
    const int h = blockIdx.y;
    const int tile = (int)gridDim.x - 1 - (int)blockIdx.x;  // LPT
    const int i0 = tile * 64;
    const int t = threadIdx.x;
    const int w = t >> 6, lane = t & 63;
    const int lr = lane & 15, quad = lane >> 4;
    const int iw0 = i0 + w * 16;

    __shared__ __align__(16) ushort_t Ks[64 * LSK];   // 17408 B
    __shared__ __align__(16) ushort_t Vt[128 * LSV];  // 18432 B
    __shared__ __align__(16) ushort_t Ps[64 * LSP];   //  9216 B

    const int lm = d_LINEMASK[h];
    const int r0 = d_R[h][0], r1 = d_R[h][1], r2 = d_R[h][2];
    const float scale = 0.08838834764831845f;
    const int dim0 = w * 32;   // this wave's 32-dim staging slice

    // Q A-frags: lane holds Q[iw0+lr][f*32 + quad*8 + (0..7)]
    bf16x8 qf[4];
    {
        const ushort_t* qrow = Qb + (size_t)(iw0 + lr) * D_MODEL + h * 128;
#pragma unroll
        for (int f = 0; f < 4; f++)
            qf[f] = *(const bf16x8*)(qrow + f * 32 + quad * 8);
    }

    f32x4 O[8];
#pragma unroll
    for (int dt = 0; dt < 8; dt++) O[dt] = (f32x4){0.f, 0.f, 0.f, 0.f};
    float m[4] = {-1e30f, -1e30f, -1e30f, -1e30f};
    float l[4] = {0.f, 0.f, 0.f, 0.f};

    const int imax = i0 + 63;
    const int ncomp = (imax - r0) / 7 + (imax - r1) / 7 + (imax - r2) / 7 + 3;
    const int nch = (ncomp + 63) >> 6;
    const int ntot = nch + 2;   // + two linear band chunks (local window)

    // j for chunk cc, key-slot = this lane
    auto jchunk = [&](int cc) -> int {
        if (cc >= nch) return ((cc == nch) ? i0 - 16 : i0 + 48) + lane;
        return jof(cc * 64 + lane, r0, r1, r2);
    };

    // gather K/V slice (32 dims at dim0) of key j into regs; OOR -> zeros
    uint4 kreg[4], vreg[4];
    auto prefetch = [&](int j) {
        if (j >= 0 && j < T_SEQ) {
            const ushort_t* kp = Kb + (size_t)j * D_MODEL + h * 128 + dim0;
            const ushort_t* vp = Vb + (size_t)j * D_MODEL + h * 128 + dim0;
#pragma unroll
            for (int v = 0; v < 4; v++) {
                kreg[v] = *(const uint4*)(kp + v * 8);
                vreg[v] = *(const uint4*)(vp + v * 8);
            }
        } else {
            uint4 zz = {0u, 0u, 0u, 0u};
#pragma unroll
            for (int v = 0; v < 4; v++) { kreg[v] = zz; vreg[v] = zz; }
        }
    };

    prefetch(jchunk(0));   // prologue

    for (int cc = 0; cc < ntot; cc++) {
        const bool band = (cc >= nch);
        const int base = band ? 0 : cc * 64;
        const int jbase = (cc == nch) ? i0 - 16 : i0 + 48;

        __syncthreads();   // prev chunk's LDS reads complete
        // publish prefetched K/V regs to LDS (lane = key slot)
#pragma unroll
        for (int v = 0; v < 4; v++) {
            *(uint4*)&Ks[lane * LSK + dim0 + v * 8] = kreg[v];
            ushort_t* vtcol = &Vt[(dim0 + v * 8) * LSV + lane];
            uint4 vv = vreg[v];
            vtcol[0 * LSV] = (ushort_t)(vv.x & 0xFFFFu);
            vtcol[1 * LSV] = (ushort_t)(vv.x >> 16);
            vtcol[2 * LSV] = (ushort_t)(vv.y & 0xFFFFu);
            vtcol[3 * LSV] = (ushort_t)(vv.y >> 16);
            vtcol[4 * LSV] = (ushort_t)(vv.z & 0xFFFFu);
            vtcol[5 * LSV] = (ushort_t)(vv.z >> 16);
            vtcol[6 * LSV] = (ushort_t)(vv.w & 0xFFFFu);
            vtcol[7 * LSV] = (ushort_t)(vv.w >> 16);
        }
        __syncthreads();

        // issue next chunk's gather NOW — overlaps with compute below
        if (cc + 1 < ntot) prefetch(jchunk(cc + 1));

        // wave-uniform skip: chunk min j beyond this wave's rows
        {
            int jmin = band ? jbase : jof(base, r0, r1, r2);
            if (jmin > iw0 + 15) continue;
        }

        // S = Q K^T over 4 tiles of 16 keys
        f32x4 S[4];
#pragma unroll
        for (int tn = 0; tn < 4; tn++) S[tn] = (f32x4){0.f, 0.f, 0.f, 0.f};
#pragma unroll
        for (int f = 0; f < 4; f++) {
            bf16x8 kf[4];
#pragma unroll
            for (int tn = 0; tn < 4; tn++)
                kf[tn] = *(const bf16x8*)&Ks[(tn * 16 + lr) * LSK + f * 32 + quad * 8];
#pragma unroll
            for (int tn = 0; tn < 4; tn++)
                S[tn] = __builtin_amdgcn_mfma_f32_16x16x32_bf16(qf[f], kf[tn], S[tn], 0, 0, 0);
        }

        // mask. fano: j<=i. band: 0<=j<=i, j>=i-16, j%7 not in line (disjoint).
#pragma unroll
        for (int tn = 0; tn < 4; tn++) {
            int j;
            bool okl = true;
            if (band) {
                j = jbase + tn * 16 + lr;
                int jm = ((j % 7) + 7) % 7;
                okl = (j >= 0) && !((lm >> jm) & 1);
            } else {
                j = jof(base + tn * 16 + lr, r0, r1, r2);
            }
#pragma unroll
            for (int r = 0; r < 4; r++) {
                int ir = iw0 + quad * 4 + r;
                bool ok = okl && (j <= ir) && (!band || j >= ir - 16);
                S[tn][r] = ok ? S[tn][r] * scale : -1e30f;
            }
        }

        // online softmax (row = (quad, r); key-reduce across lr via shfl)
        float a4[4], pvv[4][4];
#pragma unroll
        for (int r = 0; r < 4; r++) {
            float cm = fmaxf(fmaxf(S[0][r], S[1][r]), fmaxf(S[2][r], S[3][r]));
            cm = fmaxf(cm, __shfl_xor(cm, 1));
            cm = fmaxf(cm, __shfl_xor(cm, 2));
            cm = fmaxf(cm, __shfl_xor(cm, 4));
            cm = fmaxf(cm, __shfl_xor(cm, 8));
            float mn = fmaxf(fmaxf(m[r], cm), -60.f);  // all-masked -> exact 0
            a4[r] = __expf(m[r] - mn);
            m[r] = mn;
            float rs_ = 0.f;
#pragma unroll
            for (int tn = 0; tn < 4; tn++) {
                pvv[tn][r] = __expf(S[tn][r] - mn);
                rs_ += pvv[tn][r];
            }
            rs_ += __shfl_xor(rs_, 1);
            rs_ += __shfl_xor(rs_, 2);
            rs_ += __shfl_xor(rs_, 4);
            rs_ += __shfl_xor(rs_, 8);
            l[r] = l[r] * a4[r] + rs_;
            ushort_t* pp = &Ps[(w * 16 + quad * 4 + r) * LSP + lr];
            pp[0]  = (ushort_t)f2bf(pvv[0][r]);
            pp[16] = (ushort_t)f2bf(pvv[1][r]);
            pp[32] = (ushort_t)f2bf(pvv[2][r]);
            pp[48] = (ushort_t)f2bf(pvv[3][r]);
        }
#pragma unroll
        for (int dt = 0; dt < 8; dt++)
#pragma unroll
            for (int r = 0; r < 4; r++) O[dt][r] *= a4[r];

        // P (A-frag via LDS round-trip, wave-private Ps rows) x Vt
        bf16x8 pf0 = *(const bf16x8*)&Ps[(w * 16 + lr) * LSP + quad * 8];
        bf16x8 pf1 = *(const bf16x8*)&Ps[(w * 16 + lr) * LSP + 32 + quad * 8];
#pragma unroll
        for (int dt = 0; dt < 8; dt++) {
            bf16x8 v0 = *(const bf16x8*)&Vt[(dt * 16 + lr) * LSV + quad * 8];
            bf16x8 v1 = *(const bf16x8*)&Vt[(dt * 16 + lr) * LSV + 32 + quad * 8];
            O[dt] = __builtin_amdgcn_mfma_f32_16x16x32_bf16(pf0, v0, O[dt], 0, 0, 0);
            O[dt] = __builtin_amdgcn_mfma_f32_16x16x32_bf16(pf1, v1, O[dt], 0, 0, 0);
        }
    }

    // finalize (l > 0: j==i always attendable)
    float inv[4];
#pragma unroll
    for (int r = 0; r < 4; r++) inv[r] = 1.f / l[r];
#pragma unroll
    for (int dt = 0; dt < 8; dt++)
#pragma unroll
        for (int r = 0; r < 4; r++) {
            int row = iw0 + quad * 4 + r;
            int col = h * 128 + dt * 16 + lr;
            Ab[(size_t)row * D_MODEL + col] = (ushort_t)f2bf(O[dt][r] * inv[r]);
        }
}

extern "C" void kernel_launch(void* const* d_in, const int* in_sizes, int n_in,
                              void* d_out, int out_size, void* d_ws, size_t ws_size,
                              hipStream_t stream) {
    const float* x  = (const float*)d_in[0];   // fp32 [4096, 896]
    const float* Wq = (const float*)d_in[1];   // fp32 [896, 896]
    const float* Wk = (const float*)d_in[2];
    const float* Wv = (const float*)d_in[3];
    const float* Wo = (const float*)d_in[4];

    const size_t n  = (size_t)T_SEQ * D_MODEL;
    const size_t nw = (size_t)D_MODEL * D_MODEL;
    ushort_t* xb  = (ushort_t*)d_ws + 128;   // 256B offset
    ushort_t* Wqb = xb + n;
    ushort_t* Wkb = Wqb + nw;
    ushort_t* Wvb = Wkb + nw;
    ushort_t* Wob = Wvb + nw;
    ushort_t* Qb  = Wob + nw;
    ushort_t* Kb  = Qb + n;
    ushort_t* Vb  = Kb + n;
    ushort_t* Ab  = Vb + n;

    // 0: fp32 -> bf16 bulk convert (x + 4 weights)
    cvt5<<<dim3(1792, 5), 256, 0, stream>>>(x, Wq, Wk, Wv, Wo,
                                            xb, Wqb, Wkb, Wvb, Wob);
    // 1: Q/K/V = x @ W^T (bf16, DMA-staged)
    gemm_nt_dma<false><<<dim3(32, 7, 3), 256, 0, stream>>>(
        xb, Wqb, Wkb, Wvb, Qb, Kb, Vb);
    // 2: sparse attention (bf16, pipelined)
    fano_attn_mfma<<<dim3(64, 7), 256, 0, stream>>>(Qb, Kb, Vb, Ab);
    // 3: out = Ab @ Wo^T -> fp32
    gemm_nt_dma<true><<<dim3(32, 7, 1), 256, 0, stream>>>(
        Ab, Wob, Wob, Wob, d_out, d_out, d_out);
}

// Round 10
// 221.612 us; speedup vs baseline: 6.1090x; 1.1355x over previous
//
#include <hip/hip_runtime.h>
#include <stdint.h>

typedef unsigned short ushort_t;
typedef __bf16 bf16x8 __attribute__((ext_vector_type(8)));
typedef float f32x4 __attribute__((ext_vector_type(4)));

#define T_SEQ 4096
#define D_MODEL 896
#define NSPLIT 4

// Attention LDS strides (u16 units, 8-multiples for ds_read_b128 alignment).
#define LSK 136   // 68 dwords/row
#define LSV 72    // 36 dwords/row; lane=key scatter spans all 32 banks
#define LSP 72

// Fano lines, residues sorted ascending per head
__constant__ int d_LINEMASK[7] = {0x07, 0x19, 0x61, 0x2A, 0x52, 0x4C, 0x34};
__constant__ int d_R[7][3] = {{0,1,2},{0,3,4},{0,5,6},{1,3,5},{1,4,6},{2,3,6},{2,4,5}};

__device__ inline unsigned f2bf(float f) {
    unsigned x = __float_as_uint(f);
    return (x + 0x7fffu + ((x >> 16) & 1u)) >> 16;   // RNE
}
__device__ inline float lo_f(unsigned x) { return __uint_as_float(x << 16); }
__device__ inline float hi_f(unsigned x) { return __uint_as_float(x & 0xFFFF0000u); }

// ---------------------------------------------------------------------------
// fp32 -> bf16 bulk convert, 5 tensors (x, Wq, Wk, Wv, Wo). 8 elem/thread.
// ---------------------------------------------------------------------------
__global__ __launch_bounds__(256)
void cvt5(const float* __restrict__ x,  const float* __restrict__ wq,
          const float* __restrict__ wk, const float* __restrict__ wv,
          const float* __restrict__ wo,
          ushort_t* __restrict__ xb,  ushort_t* __restrict__ wqb,
          ushort_t* __restrict__ wkb, ushort_t* __restrict__ wvb,
          ushort_t* __restrict__ wob) {
    const int ten = blockIdx.y;
    const float* s = (ten == 0) ? x : (ten == 1) ? wq : (ten == 2) ? wk
                   : (ten == 3) ? wv : wo;
    ushort_t* d = (ten == 0) ? xb : (ten == 1) ? wqb : (ten == 2) ? wkb
                : (ten == 3) ? wvb : wob;
    const int n8 = ((ten == 0) ? T_SEQ * D_MODEL : D_MODEL * D_MODEL) >> 3;
    for (int i = blockIdx.x * 256 + threadIdx.x; i < n8; i += gridDim.x * 256) {
        float4 a = ((const float4*)s)[2 * i];
        float4 b = ((const float4*)s)[2 * i + 1];
        uint4 u;
        u.x = f2bf(a.x) | (f2bf(a.y) << 16);
        u.y = f2bf(a.z) | (f2bf(a.w) << 16);
        u.z = f2bf(b.x) | (f2bf(b.y) << 16);
        u.w = f2bf(b.z) | (f2bf(b.w) << 16);
        ((uint4*)d)[i] = u;
    }
}

// async global->LDS DMA, 16 B/lane. LDS dest = wave-uniform base + lane*16.
__device__ __forceinline__ void async_cp16(const void* g, void* l) {
    __builtin_amdgcn_global_load_lds(
        (__attribute__((address_space(1))) void*)g,
        (__attribute__((address_space(3))) void*)l,
        16, 0, 0);
}

// ---------------------------------------------------------------------------
// C[M,N] = A[M,K] @ B[N,K]^T, bf16 in, fp32 acc, bf16/fp32 out (R9-verified).
// m97 structure: 128x128 tile, BK=32, DMA staging. z selects (B,C) pair.
// ---------------------------------------------------------------------------
template <bool C32>
__global__ __launch_bounds__(256)
void gemm_nt_dma(const ushort_t* __restrict__ A,
                 const ushort_t* __restrict__ B0,
                 const ushort_t* __restrict__ B1,
                 const ushort_t* __restrict__ B2,
                 void* __restrict__ C0,
                 void* __restrict__ C1,
                 void* __restrict__ C2) {
    const int z = blockIdx.z;
    const ushort_t* B = (z == 0) ? B0 : (z == 1) ? B1 : B2;
    void* C = (z == 0) ? C0 : (z == 1) ? C1 : C2;

    const int K = D_MODEL, N = D_MODEL;
    const int i0 = blockIdx.x * 128;
    const int n0 = blockIdx.y * 128;

    __shared__ __align__(16) ushort_t As[128 * 32];   // NO padding (DMA layout)
    __shared__ __align__(16) ushort_t Bs[128 * 32];

    const int t = threadIdx.x;
    const int w = t >> 6, lane = t & 63;
    const int wm = (w >> 1) * 64, wn = (w & 1) * 64;
    const int lr = lane & 15, lq = lane >> 4;

    const int srow = w * 16 + (lane >> 2);
    const int scol = (lane & 3) * 8;
    const ushort_t* gA0 = A + (size_t)(i0 + srow) * K + scol;
    const ushort_t* gA1 = A + (size_t)(i0 + 64 + srow) * K + scol;
    const ushort_t* gB0 = B + (size_t)(n0 + srow) * K + scol;
    const ushort_t* gB1 = B + (size_t)(n0 + 64 + srow) * K + scol;
    ushort_t* lA0 = &As[(w * 16) * 32];
    ushort_t* lA1 = &As[(64 + w * 16) * 32];
    ushort_t* lB0 = &Bs[(w * 16) * 32];
    ushort_t* lB1 = &Bs[(64 + w * 16) * 32];

    f32x4 acc[4][4];
#pragma unroll
    for (int a = 0; a < 4; a++)
#pragma unroll
        for (int b = 0; b < 4; b++) acc[a][b] = (f32x4){0.f, 0.f, 0.f, 0.f};

    for (int k0 = 0; k0 < K; k0 += 32) {
        __syncthreads();
        async_cp16(gA0 + k0, lA0);
        async_cp16(gA1 + k0, lA1);
        async_cp16(gB0 + k0, lB0);
        async_cp16(gB1 + k0, lB1);
        __builtin_amdgcn_s_waitcnt(0);
        __syncthreads();

        bf16x8 af[4], bfr[4];
#pragma unroll
        for (int mi = 0; mi < 4; mi++)
            af[mi] = *(const bf16x8*)&As[(wm + mi * 16 + lr) * 32 + lq * 8];
#pragma unroll
        for (int ni = 0; ni < 4; ni++)
            bfr[ni] = *(const bf16x8*)&Bs[(wn + ni * 16 + lr) * 32 + lq * 8];
#pragma unroll
        for (int mi = 0; mi < 4; mi++)
#pragma unroll
            for (int ni = 0; ni < 4; ni++)
                acc[mi][ni] = __builtin_amdgcn_mfma_f32_16x16x32_bf16(
                    af[mi], bfr[ni], acc[mi][ni], 0, 0, 0);
    }

    // C/D layout: col = lane&15, row = (lane>>4)*4 + reg
    if (C32) {
        float* Cf = (float*)C;
#pragma unroll
        for (int mi = 0; mi < 4; mi++)
#pragma unroll
            for (int ni = 0; ni < 4; ni++)
#pragma unroll
                for (int r = 0; r < 4; r++) {
                    int row = i0 + wm + mi * 16 + lq * 4 + r;
                    int col = n0 + wn + ni * 16 + lr;
                    Cf[(size_t)row * N + col] = acc[mi][ni][r];
                }
    } else {
        ushort_t* Cb = (ushort_t*)C;
#pragma unroll
        for (int mi = 0; mi < 4; mi++)
#pragma unroll
            for (int ni = 0; ni < 4; ni++)
#pragma unroll
                for (int r = 0; r < 4; r++) {
                    int row = i0 + wm + mi * 16 + lq * 4 + r;
                    int col = n0 + wn + ni * 16 + lr;
                    Cb[(size_t)row * N + col] = (ushort_t)f2bf(acc[mi][ni][r]);
                }
    }
}

// scatter 8 dims of one key's V into Vt[d][key] (stride LSV); lane=key mapping
__device__ inline void vt_scatter8(ushort_t* vtcol, uint4 vv) {
    vtcol[0 * LSV] = (ushort_t)(vv.x & 0xFFFFu);
    vtcol[1 * LSV] = (ushort_t)(vv.x >> 16);
    vtcol[2 * LSV] = (ushort_t)(vv.y & 0xFFFFu);
    vtcol[3 * LSV] = (ushort_t)(vv.y >> 16);
    vtcol[4 * LSV] = (ushort_t)(vv.z & 0xFFFFu);
    vtcol[5 * LSV] = (ushort_t)(vv.z >> 16);
    vtcol[6 * LSV] = (ushort_t)(vv.w & 0xFFFFu);
    vtcol[7 * LSV] = (ushort_t)(vv.w >> 16);
}

// stage 32 dims of key j (slot kk) into Ks (row-major) and Vt (transposed);
// OOR j -> zeros. (R6/R8-proven direct staging — register prefetch reverted.)
__device__ inline void stage_kv(const ushort_t* __restrict__ Kb,
                                const ushort_t* __restrict__ Vb,
                                ushort_t* Ks, ushort_t* Vt,
                                int j, int kk, int dim0, int h) {
    if (j >= 0 && j < T_SEQ) {
        const ushort_t* kp = Kb + (size_t)j * D_MODEL + h * 128 + dim0;
        const ushort_t* vp = Vb + (size_t)j * D_MODEL + h * 128 + dim0;
#pragma unroll
        for (int v = 0; v < 4; v++) {
            *(uint4*)&Ks[kk * LSK + dim0 + v * 8] = *(const uint4*)(kp + v * 8);
            vt_scatter8(&Vt[(dim0 + v * 8) * LSV + kk], *(const uint4*)(vp + v * 8));
        }
    } else {
        uint4 zz = {0u, 0u, 0u, 0u};
#pragma unroll
        for (int v = 0; v < 4; v++) {
            *(uint4*)&Ks[kk * LSK + dim0 + v * 8] = zz;
            vt_scatter8(&Vt[(dim0 + v * 8) * LSV + kk], zz);
        }
    }
}

// compacted-index -> key: p -> j = 7*(p/3) + r[p%3]
__device__ inline int jof(int p, int r0, int r1, int r2) {
    int g = p / 3, rs = p - 3 * g;
    return 7 * g + ((rs == 0) ? r0 : (rs == 1) ? r1 : r2);
}

// ---------------------------------------------------------------------------
// Split-K MFMA Fano attention. Grid (64 tiles [x-reversed], 7 heads, 4 splits).
// Block = (head, 64 q-rows, chunk sub-range); wave = 16 rows. Chunk list =
// nch fano-compacted 64-key chunks + 2 band chunks; split s runs
// [s*ntot/4, (s+1)*ntot/4). Writes unnormalized partials:
//   Opart[s][h][row][128] (bf16), Lm[s][h][row][{m,l}] (fp32).
// LDS 45 KB -> 3 blocks/CU; 1792 blocks total -> chains overlap.
// ---------------------------------------------------------------------------
__global__ __launch_bounds__(256, 3)
void fano_attn_split(const ushort_t* __restrict__ Qb,
                     const ushort_t* __restrict__ Kb,
                     const ushort_t* __restrict__ Vb,
                     ushort_t* __restrict__ Opart,
                     float* __restrict__ Lm) {
    const int h = blockIdx.y;
    const int sp = blockIdx.z;
    const int tile = (int)gridDim.x - 1 - (int)blockIdx.x;  // LPT
    const int i0 = tile * 64;
    const int t = threadIdx.x;
    const int w = t >> 6, lane = t & 63;
    const int lr = lane & 15, quad = lane >> 4;
    const int iw0 = i0 + w * 16;

    __shared__ __align__(16) ushort_t Ks[64 * LSK];   // 17408 B
    __shared__ __align__(16) ushort_t Vt[128 * LSV];  // 18432 B
    __shared__ __align__(16) ushort_t Ps[64 * LSP];   //  9216 B

    const int lm = d_LINEMASK[h];
    const int r0 = d_R[h][0], r1 = d_R[h][1], r2 = d_R[h][2];
    const float scale = 0.08838834764831845f;

    // Q A-frags: lane holds Q[iw0+lr][f*32 + quad*8 + (0..7)]
    bf16x8 qf[4];
    {
        const ushort_t* qrow = Qb + (size_t)(iw0 + lr) * D_MODEL + h * 128;
#pragma unroll
        for (int f = 0; f < 4; f++)
            qf[f] = *(const bf16x8*)(qrow + f * 32 + quad * 8);
    }

    f32x4 O[8];
#pragma unroll
    for (int dt = 0; dt < 8; dt++) O[dt] = (f32x4){0.f, 0.f, 0.f, 0.f};
    float m[4] = {-1e30f, -1e30f, -1e30f, -1e30f};
    float l[4] = {0.f, 0.f, 0.f, 0.f};

    const int imax = i0 + 63;
    const int ncomp = (imax - r0) / 7 + (imax - r1) / 7 + (imax - r2) / 7 + 3;
    const int nch = (ncomp + 63) >> 6;
    const int ntot = nch + 2;                 // + two linear band chunks
    const int cstart = (sp * ntot) / NSPLIT;  // this split's chunk sub-range
    const int cend = ((sp + 1) * ntot) / NSPLIT;

    for (int cc = cstart; cc < cend; cc++) {
        const bool band = (cc >= nch);
        const int base = band ? 0 : cc * 64;
        const int jbase = (cc == nch) ? i0 - 16 : i0 + 48;

        __syncthreads();   // prev chunk's LDS reads complete
        {   // stage 64 keys; wave w covers dims [w*32, w*32+32)
            int j = band ? (jbase + lane) : jof(base + lane, r0, r1, r2);
            stage_kv(Kb, Vb, Ks, Vt, j, lane, w * 32, h);
        }
        __syncthreads();

        // wave-uniform skip: chunk min j beyond this wave's rows
        {
            int jmin = band ? jbase : jof(base, r0, r1, r2);
            if (jmin > iw0 + 15) continue;
        }

        // S = Q K^T over 4 tiles of 16 keys
        f32x4 S[4];
#pragma unroll
        for (int tn = 0; tn < 4; tn++) S[tn] = (f32x4){0.f, 0.f, 0.f, 0.f};
#pragma unroll
        for (int f = 0; f < 4; f++) {
            bf16x8 kf[4];
#pragma unroll
            for (int tn = 0; tn < 4; tn++)
                kf[tn] = *(const bf16x8*)&Ks[(tn * 16 + lr) * LSK + f * 32 + quad * 8];
#pragma unroll
            for (int tn = 0; tn < 4; tn++)
                S[tn] = __builtin_amdgcn_mfma_f32_16x16x32_bf16(qf[f], kf[tn], S[tn], 0, 0, 0);
        }

        // mask. fano: j<=i. band: 0<=j<=i, j>=i-16, j%7 not in line (disjoint).
#pragma unroll
        for (int tn = 0; tn < 4; tn++) {
            int j;
            bool okl = true;
            if (band) {
                j = jbase + tn * 16 + lr;
                int jm = ((j % 7) + 7) % 7;
                okl = (j >= 0) && !((lm >> jm) & 1);
            } else {
                j = jof(base + tn * 16 + lr, r0, r1, r2);
            }
#pragma unroll
            for (int r = 0; r < 4; r++) {
                int ir = iw0 + quad * 4 + r;
                bool ok = okl && (j <= ir) && (!band || j >= ir - 16);
                S[tn][r] = ok ? S[tn][r] * scale : -1e30f;
            }
        }

        // online softmax (row = (quad, r); key-reduce across lr via shfl)
        float a4[4], pvv[4][4];
#pragma unroll
        for (int r = 0; r < 4; r++) {
            float cm = fmaxf(fmaxf(S[0][r], S[1][r]), fmaxf(S[2][r], S[3][r]));
            cm = fmaxf(cm, __shfl_xor(cm, 1));
            cm = fmaxf(cm, __shfl_xor(cm, 2));
            cm = fmaxf(cm, __shfl_xor(cm, 4));
            cm = fmaxf(cm, __shfl_xor(cm, 8));
            float mn = fmaxf(fmaxf(m[r], cm), -60.f);  // all-masked -> exact 0
            a4[r] = __expf(m[r] - mn);
            m[r] = mn;
            float rs_ = 0.f;
#pragma unroll
            for (int tn = 0; tn < 4; tn++) {
                pvv[tn][r] = __expf(S[tn][r] - mn);
                rs_ += pvv[tn][r];
            }
            rs_ += __shfl_xor(rs_, 1);
            rs_ += __shfl_xor(rs_, 2);
            rs_ += __shfl_xor(rs_, 4);
            rs_ += __shfl_xor(rs_, 8);
            l[r] = l[r] * a4[r] + rs_;
            ushort_t* pp = &Ps[(w * 16 + quad * 4 + r) * LSP + lr];
            pp[0]  = (ushort_t)f2bf(pvv[0][r]);
            pp[16] = (ushort_t)f2bf(pvv[1][r]);
            pp[32] = (ushort_t)f2bf(pvv[2][r]);
            pp[48] = (ushort_t)f2bf(pvv[3][r]);
        }
#pragma unroll
        for (int dt = 0; dt < 8; dt++)
#pragma unroll
            for (int r = 0; r < 4; r++) O[dt][r] *= a4[r];

        // P (A-frag via LDS round-trip, wave-private Ps rows) x Vt
        bf16x8 pf0 = *(const bf16x8*)&Ps[(w * 16 + lr) * LSP + quad * 8];
        bf16x8 pf1 = *(const bf16x8*)&Ps[(w * 16 + lr) * LSP + 32 + quad * 8];
#pragma unroll
        for (int dt = 0; dt < 8; dt++) {
            bf16x8 v0 = *(const bf16x8*)&Vt[(dt * 16 + lr) * LSV + quad * 8];
            bf16x8 v1 = *(const bf16x8*)&Vt[(dt * 16 + lr) * LSV + 32 + quad * 8];
            O[dt] = __builtin_amdgcn_mfma_f32_16x16x32_bf16(pf0, v0, O[dt], 0, 0, 0);
            O[dt] = __builtin_amdgcn_mfma_f32_16x16x32_bf16(pf1, v1, O[dt], 0, 0, 0);
        }
    }

    // write unnormalized partials
    const size_t pbase = ((size_t)sp * 7 + h) * T_SEQ;
#pragma unroll
    for (int dt = 0; dt < 8; dt++)
#pragma unroll
        for (int r = 0; r < 4; r++) {
            int row = iw0 + quad * 4 + r;
            Opart[(pbase + row) * 128 + dt * 16 + lr] = (ushort_t)f2bf(O[dt][r]);
        }
    if (lr == 0) {
#pragma unroll
        for (int r = 0; r < 4; r++) {
            int row = iw0 + quad * 4 + r;
            Lm[(pbase + row) * 2 + 0] = m[r];
            Lm[(pbase + row) * 2 + 1] = l[r];
        }
    }
}

// ---------------------------------------------------------------------------
// Merge NSPLIT partials -> Ab (bf16). Grid (64,7), block 256.
// Thread = (row = t>>2, 32-dim slice = (t&3)*32).
// ---------------------------------------------------------------------------
__global__ __launch_bounds__(256)
void attn_merge(const ushort_t* __restrict__ Opart,
                const float* __restrict__ Lm,
                ushort_t* __restrict__ Ab) {
    const int h = blockIdx.y;
    const int row = blockIdx.x * 64 + (threadIdx.x >> 2);
    const int d0 = (threadIdx.x & 3) * 32;

    float ms[NSPLIT], ls[NSPLIT], M = -1e30f;
#pragma unroll
    for (int s = 0; s < NSPLIT; s++) {
        size_t pb = (((size_t)s * 7 + h) * T_SEQ + row) * 2;
        ms[s] = Lm[pb];
        ls[s] = Lm[pb + 1];
        M = fmaxf(M, ms[s]);
    }
    float L = 0.f, c[NSPLIT];
#pragma unroll
    for (int s = 0; s < NSPLIT; s++) {
        c[s] = __expf(ms[s] - M);
        L += c[s] * ls[s];
    }
    float acc[32];
#pragma unroll
    for (int k = 0; k < 32; k++) acc[k] = 0.f;
#pragma unroll
    for (int s = 0; s < NSPLIT; s++) {
        const ushort_t* op = Opart + (((size_t)s * 7 + h) * T_SEQ + row) * 128 + d0;
#pragma unroll
        for (int v = 0; v < 4; v++) {
            uint4 u = *(const uint4*)(op + v * 8);
            acc[v * 8 + 0] += c[s] * lo_f(u.x);
            acc[v * 8 + 1] += c[s] * hi_f(u.x);
            acc[v * 8 + 2] += c[s] * lo_f(u.y);
            acc[v * 8 + 3] += c[s] * hi_f(u.y);
            acc[v * 8 + 4] += c[s] * lo_f(u.z);
            acc[v * 8 + 5] += c[s] * hi_f(u.z);
            acc[v * 8 + 6] += c[s] * lo_f(u.w);
            acc[v * 8 + 7] += c[s] * hi_f(u.w);
        }
    }
    float invL = 1.f / L;   // L > 0: j==i lies in some split
    ushort_t* dst = Ab + (size_t)row * D_MODEL + h * 128 + d0;
#pragma unroll
    for (int v = 0; v < 4; v++) {
        uint4 u;
        u.x = f2bf(acc[v * 8 + 0] * invL) | (f2bf(acc[v * 8 + 1] * invL) << 16);
        u.y = f2bf(acc[v * 8 + 2] * invL) | (f2bf(acc[v * 8 + 3] * invL) << 16);
        u.z = f2bf(acc[v * 8 + 4] * invL) | (f2bf(acc[v * 8 + 5] * invL) << 16);
        u.w = f2bf(acc[v * 8 + 6] * invL) | (f2bf(acc[v * 8 + 7] * invL) << 16);
        *(uint4*)(dst + v * 8) = u;
    }
}

extern "C" void kernel_launch(void* const* d_in, const int* in_sizes, int n_in,
                              void* d_out, int out_size, void* d_ws, size_t ws_size,
                              hipStream_t stream) {
    const float* x  = (const float*)d_in[0];   // fp32 [4096, 896]
    const float* Wq = (const float*)d_in[1];   // fp32 [896, 896]
    const float* Wk = (const float*)d_in[2];
    const float* Wv = (const float*)d_in[3];
    const float* Wo = (const float*)d_in[4];

    const size_t n  = (size_t)T_SEQ * D_MODEL;
    const size_t nw = (size_t)D_MODEL * D_MODEL;
    ushort_t* xb  = (ushort_t*)d_ws + 128;   // 256B offset
    ushort_t* Wqb = xb + n;
    ushort_t* Wkb = Wqb + nw;
    ushort_t* Wvb = Wkb + nw;
    ushort_t* Wob = Wvb + nw;
    ushort_t* Qb  = Wob + nw;
    ushort_t* Kb  = Qb + n;
    ushort_t* Vb  = Kb + n;
    ushort_t* Ab  = Vb + n;
    ushort_t* Opart = Ab + n;                          // 4*7*4096*128 bf16
    float*    Lm  = (float*)(Opart + (size_t)NSPLIT * 7 * T_SEQ * 128);

    // 0: fp32 -> bf16 bulk convert (x + 4 weights)
    cvt5<<<dim3(1792, 5), 256, 0, stream>>>(x, Wq, Wk, Wv, Wo,
                                            xb, Wqb, Wkb, Wvb, Wob);
    // 1: Q/K/V = x @ W^T (bf16, DMA-staged)
    gemm_nt_dma<false><<<dim3(32, 7, 3), 256, 0, stream>>>(
        xb, Wqb, Wkb, Wvb, Qb, Kb, Vb);
    // 2: split-K sparse attention -> partials
    fano_attn_split<<<dim3(64, 7, NSPLIT), 256, 0, stream>>>(
        Qb, Kb, Vb, Opart, Lm);
    // 3: merge partials -> Ab
    attn_merge<<<dim3(64, 7), 256, 0, stream>>>(Opart, Lm, Ab);
    // 4: out = Ab @ Wo^T -> fp32
    gemm_nt_dma<true><<<dim3(32, 7, 1), 256, 0, stream>>>(
        Ab, Wob, Wob, Wob, d_out, d_out, d_out);
}